// Round 5
// baseline (433.104 us; speedup 1.0000x reference)
//
#include <hip/hip_runtime.h>

#define N_NODES 100000
#define N_EDGES 1600000
#define D 128
#define CB 98       // coarse buckets of 1024 rows (ceil(100000/1024))
#define CCAP 17920  // per-bucket capacity: mean 16384, sigma 128 -> +12 sigma

typedef unsigned short u16;
typedef unsigned int u32;
typedef __attribute__((ext_vector_type(8))) short bf16x8;
typedef __attribute__((ext_vector_type(4))) float f32x4;

__device__ __forceinline__ u16 f2bf(float f) {
    u32 u = __float_as_uint(f);
    u += 0x7fffu + ((u >> 16) & 1u);  // round-to-nearest-even
    return (u16)(u >> 16);
}

// ---------------- fused front end: bin_pass | convert_feat | convert_w ----------------
// Coarse binning: 98 buckets x 1024 rows. Per 4096-edge block: LDS hist over 98
// counters, ONE returning device atomic per (block,bucket) = 38K total.
// coarseCount padded to 1 counter/cacheline. Scatter: ~42 consecutive edges per
// bucket per block -> near-full-line writes (no RMW write amplification).

#define BIN_BLKS 391  // ceil(E/4096)
#define CF_BLKS 6250  // N*D/8/256
#define CW_BLKS 128   // 32768/256

__global__ __launch_bounds__(256) void prep(
    const float* __restrict__ features, u32* __restrict__ featb,
    const float* __restrict__ W1, const float* __restrict__ W2,
    u16* __restrict__ W1t, u16* __restrict__ W2t,
    const int* __restrict__ row, const int* __restrict__ col,
    const float* __restrict__ val,
    int* __restrict__ coarseCount, int2* __restrict__ binned) {
    __shared__ int h[CB];
    __shared__ int lb[CB];
    int bid = blockIdx.x;
    int t = threadIdx.x;

    if (bid >= BIN_BLKS) {
        int cid = bid - BIN_BLKS;
        if (cid < CF_BLKS) {
            // features fp32 [N,128] -> bf16 packed (word j = cols {2j,2j+1})
            int idx = cid * 256 + t;  // [0, N*D/8)
            const float4* f4 = (const float4*)features;
            float4 a = f4[idx * 2], b = f4[idx * 2 + 1];
            uint4 o;
            o.x = (u32)f2bf(a.x) | ((u32)f2bf(a.y) << 16);
            o.y = (u32)f2bf(a.z) | ((u32)f2bf(a.w) << 16);
            o.z = (u32)f2bf(b.x) | ((u32)f2bf(b.y) << 16);
            o.w = (u32)f2bf(b.z) | ((u32)f2bf(b.w) << 16);
            ((uint4*)featb)[idx] = o;
        } else {
            // W[k][n] fp32 -> Wt[n][k] bf16, both 128x128
            int flat = (cid - CF_BLKS) * 256 + t;  // [0, 32768)
            int m = flat >> 14;
            int idx = flat & 16383;
            int n = idx & 127;
            int k = idx >> 7;
            const float* src = m ? W2 : W1;
            u16* dst = m ? W2t : W1t;
            dst[n * 128 + k] = f2bf(src[k * 128 + n]);
        }
        return;
    }

    // bin_pass: append edges into coarse buckets; pack row-local (10b) into
    // col's high bits (col < 2^17)
    if (t < CB) h[t] = 0;
    __syncthreads();
    int base = bid * 4096;
    int r[16];
#pragma unroll
    for (int i = 0; i < 16; ++i) {
        int e = base + i * 256 + t;
        r[i] = (e < N_EDGES) ? row[e] : -1;
        if (r[i] >= 0) atomicAdd(&h[r[i] >> 10], 1);
    }
    __syncthreads();
    if (t < CB) {
        int c = h[t];
        lb[t] = c ? atomicAdd(&coarseCount[t * 16], c) : 0;  // padded: 1/line
        h[t] = 0;                                            // reuse as cursor
    }
    __syncthreads();
#pragma unroll
    for (int i = 0; i < 16; ++i) {
        if (r[i] < 0) continue;
        int e = base + i * 256 + t;
        int cb = r[i] >> 10;
        int pos = cb * CCAP + lb[cb] + atomicAdd(&h[cb], 1);
        int2 ev;
        ev.x = col[e] | ((r[i] & 1023) << 17);
        ev.y = __float_as_int(val[e]);
        binned[pos] = ev;
    }
}

// ---------------- sortk: one 1024-thread block per coarse bucket ----------------
// LDS hist over 1024 row-locals -> shuffle-hierarchical exclusive scan ->
// rowRange (absolute positions into the PADDED per-bucket scev window) ->
// scatter binned -> row-sorted scev within the bucket's own ~140KB window.

__global__ __launch_bounds__(1024) void sortk(const int2* __restrict__ binned,
                                              const int* __restrict__ coarseCount,
                                              int2* __restrict__ rowRange,
                                              int2* __restrict__ scev) {
    __shared__ int h[1024];
    __shared__ int cur[1024];
    __shared__ int wsum[16];
    __shared__ int wbase[16];
    int b = blockIdx.x, t = threadIdx.x;
    int lane = t & 63, wv = t >> 6;
    int row0 = b << 10;
    int lo = b * CCAP;
    int cnt = coarseCount[b * 16];

    h[t] = 0;
    __syncthreads();
    for (int i = t; i < cnt; i += 1024)
        atomicAdd(&h[((u32)binned[lo + i].x) >> 17], 1);
    __syncthreads();

    int c = h[t];
    int x = c;  // inclusive scan within wave
#pragma unroll
    for (int d = 1; d < 64; d <<= 1) {
        int y = __shfl_up(x, d);
        if (lane >= d) x += y;
    }
    if (lane == 63) wsum[wv] = x;
    __syncthreads();
    if (t < 16) {
        int s = wsum[t], sx = s;
#pragma unroll
        for (int d = 1; d < 16; d <<= 1) {
            int y = __shfl_up(sx, d);
            if (lane >= d) sx += y;
        }
        wbase[t] = sx - s;  // exclusive base per wave
    }
    __syncthreads();
    int start = lo + wbase[wv] + (x - c);  // absolute exclusive prefix
    if (row0 + t < N_NODES) rowRange[row0 + t] = make_int2(start, start + c);
    cur[t] = start;
    __syncthreads();

    for (int i = t; i < cnt; i += 1024) {
        int2 ev = binned[lo + i];
        int rl = ((u32)ev.x) >> 17;
        int pos = atomicAdd(&cur[rl], 1);
        scev[pos] = make_int2(ev.x & 0x1FFFF, ev.y);
    }
}

// ---------------- SpMM (bf16 gather): one wave per row ----------------
// Xb[r] = bf16( featb[r] + sum_j v_j * featb[col_j] )
// wid wave-uniform via readfirstlane -> rowRange/scev stay scalar (e-batches
// live in SGPRs); clamped 16-deep batches (dup slots hit L1).
// Round-4 structure: 2-deep pipeline FORCED with sched_barrier(0) — issue the
// next batch's 16 gathers, fence, then consume the previous batch. The fence
// makes it illegal for the backend to sink the new gathers below the consume,
// so both p-buffers stay live (VGPR ~48-56) and auto waitcnts become
// vmcnt(31)..vmcnt(16): >=16 loads in flight through every consume phase
// (T4 counted-vmcnt, never drained to 0 in steady state). Round-2's VGPR-24
// build drained to 0 between batches (~200cy consume with nothing in flight
// -> 3.7 TB/s); round-3's unfenced double-buffer collapsed (VGPR 36, -8%).
// __launch_bounds__(256,8) pins <=64 VGPR so 8 waves/SIMD TLP is kept.

__global__ __launch_bounds__(256, 8) void spmm_bf16(
    const int2* __restrict__ scev, const int2* __restrict__ rowRange,
    const u32* __restrict__ featb, u32* __restrict__ Xb) {
    int wid0 = (blockIdx.x * blockDim.x + threadIdx.x) >> 6;
    int wid = __builtin_amdgcn_readfirstlane(wid0);
    int lane = threadIdx.x & 63;
    if (wid >= N_NODES) return;
    int2 rr = rowRange[wid];
    int j = rr.x, end = rr.y;
    u32 self = featb[wid * 64 + lane];
    float ax0 = __uint_as_float(self << 16);
    float ay0 = __uint_as_float(self & 0xffff0000u);
    float ax1 = 0.f, ay1 = 0.f;

    if (j < end) {
        int2 eA[16], eB[16];
        u32 pA[16], pB[16];

#define LOADE(E, JB)                                                     \
    _Pragma("unroll") for (int u = 0; u < 16; ++u) {                     \
        int idx = (JB) + u;                                              \
        int c = (idx < end) ? idx : (end - 1); /* uniform: stays SGPR */ \
        E[u] = scev[c];                                                  \
        if (idx >= end) E[u].y = 0; /* inactive slot contributes 0 */    \
    }

#define GATH(P, E)                                                       \
    _Pragma("unroll") for (int u = 0; u < 16; ++u)                       \
        P[u] = featb[E[u].x * 64 + lane];

#define CONS(E, P)                                                       \
    _Pragma("unroll") for (int u = 0; u < 16; ++u) {                     \
        float v = __int_as_float(E[u].y);                                \
        float lo = __uint_as_float(P[u] << 16);                          \
        float hi = __uint_as_float(P[u] & 0xffff0000u);                  \
        if (u & 1) { ax1 += v * lo; ay1 += v * hi; }                     \
        else       { ax0 += v * lo; ay0 += v * hi; }                     \
    }

#define SB __builtin_amdgcn_sched_barrier(0)

        int nb = (end - j + 15) >> 4;
        LOADE(eA, j);
        GATH(pA, eA);
        int jb = j + 16;
        int b = 1;
        while (b + 1 < nb) {
            LOADE(eB, jb);
            GATH(pB, eB);
            SB;  // pB gathers must issue before pA consume
            CONS(eA, pA);
            LOADE(eA, jb + 16);
            GATH(pA, eA);
            SB;  // pA' gathers must issue before pB consume
            CONS(eB, pB);
            jb += 32;
            b += 2;
        }
        if (b < nb) {
            LOADE(eB, jb);
            GATH(pB, eB);
            SB;
            CONS(eA, pA);
            CONS(eB, pB);
        } else {
            CONS(eA, pA);
        }
#undef LOADE
#undef GATH
#undef CONS
#undef SB
    }

    float accx = ax0 + ax1;
    float accy = ay0 + ay1;
    Xb[wid * 64 + lane] = (u32)f2bf(accx) | ((u32)f2bf(accy) << 16);
}

// ---------------- fused MFMA GEMM: out = relu(X@W1+b1)@W2 + b2 ----------------
// Stage 1: W1 staged in LDS, MFMA -> bias+ReLU. H never touches HBM:
// C-fragments packed as bf16 u32-pairs into a TRANSPOSED LDS tile Ht[col][row]
// aliased over Ws (W1 dead after stage 1; barrier-separated). Stage-2
// A-fragments read Ht[k][l16] conflict-free; B-fragments stream straight from
// global W2t (32 KB, L2-resident). Saves the 51.2 MB Hb round-trip + a launch.

__global__ __launch_bounds__(256, 2) void gemm_fused(
    const u16* __restrict__ Xb, const u16* __restrict__ W1t,
    const float* __restrict__ b1, const u16* __restrict__ W2t,
    const float* __restrict__ b2, float* __restrict__ outf) {
    __shared__ u16 Ws[128][136];               // 34816 B; stage 2 aliases Ht over it
    u16(*Ht)[130] = (u16(*)[130]) & Ws[0][0];  // 128x130 = 33280 B <= 34816

    int t = threadIdx.x;
    {
        const uint4* wsrc = (const uint4*)W1t;
#pragma unroll
        for (int i = 0; i < 8; ++i) {
            int f = t + 256 * i;
            *(uint4*)&Ws[f >> 4][(f & 15) << 3] = wsrc[f];
        }
    }
    __syncthreads();

    int w = t >> 6, lane = t & 63;
    int quad = lane >> 4, l16 = lane & 15;
    int row0 = blockIdx.x * 128 + w * 32;

    f32x4 acc[2][8];
#pragma unroll
    for (int rt = 0; rt < 2; ++rt)
#pragma unroll
        for (int ct = 0; ct < 8; ++ct) acc[rt][ct] = (f32x4){0.f, 0.f, 0.f, 0.f};

    int ra = row0 + l16;
    int rb = row0 + 16 + l16;
    if (ra > N_NODES - 1) ra = N_NODES - 1;
    if (rb > N_NODES - 1) rb = N_NODES - 1;
    const u16* pa = Xb + (size_t)ra * D + quad * 8;
    const u16* pb = Xb + (size_t)rb * D + quad * 8;

#pragma unroll
    for (int kb = 0; kb < 128; kb += 32) {
        bf16x8 a0 = *(const bf16x8*)(pa + kb);
        bf16x8 a1 = *(const bf16x8*)(pb + kb);
#pragma unroll
        for (int ct = 0; ct < 8; ++ct) {
            bf16x8 b = *(const bf16x8*)&Ws[ct * 16 + l16][kb + quad * 8];
            acc[0][ct] = __builtin_amdgcn_mfma_f32_16x16x32_bf16(a0, b, acc[0][ct], 0, 0, 0);
            acc[1][ct] = __builtin_amdgcn_mfma_f32_16x16x32_bf16(a1, b, acc[1][ct], 0, 0, 0);
        }
    }

    float bv1[8];
#pragma unroll
    for (int ct = 0; ct < 8; ++ct) bv1[ct] = b1[ct * 16 + l16];

    __syncthreads();  // all W1 reads complete before Ht overwrites Ws

    int hbase = w * 32;  // this wave's local row base
#pragma unroll
    for (int rt = 0; rt < 2; ++rt) {
#pragma unroll
        for (int ct = 0; ct < 8; ++ct) {
            float v0 = fmaxf(acc[rt][ct][0] + bv1[ct], 0.f);
            float v1 = fmaxf(acc[rt][ct][1] + bv1[ct], 0.f);
            float v2 = fmaxf(acc[rt][ct][2] + bv1[ct], 0.f);
            float v3 = fmaxf(acc[rt][ct][3] + bv1[ct], 0.f);
            u16* dst = &Ht[ct * 16 + l16][hbase + rt * 16 + quad * 4];
            ((u32*)dst)[0] = (u32)f2bf(v0) | ((u32)f2bf(v1) << 16);
            ((u32*)dst)[1] = (u32)f2bf(v2) | ((u32)f2bf(v3) << 16);
        }
    }
    __syncthreads();

    f32x4 acc2[2][8];
#pragma unroll
    for (int rt = 0; rt < 2; ++rt)
#pragma unroll
        for (int ct = 0; ct < 8; ++ct) acc2[rt][ct] = (f32x4){0.f, 0.f, 0.f, 0.f};

#pragma unroll
    for (int kb = 0; kb < 128; kb += 32) {
        bf16x8 a0, a1;
#pragma unroll
        for (int i = 0; i < 8; ++i) {
            a0[i] = (short)Ht[kb + quad * 8 + i][hbase + l16];
            a1[i] = (short)Ht[kb + quad * 8 + i][hbase + 16 + l16];
        }
#pragma unroll
        for (int ct = 0; ct < 8; ++ct) {
            bf16x8 b = *(const bf16x8*)(W2t + (size_t)(ct * 16 + l16) * D + kb + quad * 8);
            acc2[0][ct] = __builtin_amdgcn_mfma_f32_16x16x32_bf16(a0, b, acc2[0][ct], 0, 0, 0);
            acc2[1][ct] = __builtin_amdgcn_mfma_f32_16x16x32_bf16(a1, b, acc2[1][ct], 0, 0, 0);
        }
    }

    float bv2[8];
#pragma unroll
    for (int ct = 0; ct < 8; ++ct) bv2[ct] = b2[ct * 16 + l16];

#pragma unroll
    for (int rt = 0; rt < 2; ++rt) {
#pragma unroll
        for (int r = 0; r < 4; ++r) {
            int row = row0 + rt * 16 + quad * 4 + r;
            if (row >= N_NODES) continue;
#pragma unroll
            for (int ct = 0; ct < 8; ++ct) {
                outf[(size_t)row * D + ct * 16 + l16] = acc2[rt][ct][r] + bv2[ct];
            }
        }
    }
}

extern "C" void kernel_launch(void* const* d_in, const int* in_sizes, int n_in,
                              void* d_out, int out_size, void* d_ws, size_t ws_size,
                              hipStream_t stream) {
    const int* indices = (const int*)d_in[0];      // [2, E]
    const float* values = (const float*)d_in[1];   // [E]
    const float* features = (const float*)d_in[2]; // [N, 128]
    const float* W1 = (const float*)d_in[3];
    const float* b1 = (const float*)d_in[4];
    const float* W2 = (const float*)d_in[5];
    const float* b2 = (const float*)d_in[6];

    const int* row = indices;
    const int* col = indices + N_EDGES;

    // ws (ints): coarseCount[CB*16] pad | rowRange[N] int2 | scev[CB*CCAP] int2 |
    //            Xb[N*64] u32 | W1t/W2t u16     total ~40.5 MB
    int* wsI = (int*)d_ws;
    int* coarseCount = wsI;                        // CB*16 = 1568 ints (1/line)
    int2* rowRange = (int2*)(wsI + 1600);          // 800 KB
    int2* scev = (int2*)(wsI + 1600 + 2 * N_NODES);  // 14.05 MB
    u32* Xb = (u32*)(wsI + 1600 + 2 * N_NODES + 2 * CB * CCAP);  // 25.6 MB, 16B-aligned
    u16* W1t = (u16*)(Xb + (size_t)N_NODES * 64);
    u16* W2t = W1t + 16384;

    // d_out: binned[CB*CCAP] int2 (14.05 MB, dead after sortk) lower part;
    // featb (bf16 features, 25.6 MB, dead after spmm) upper half;
    // gemm_fused overwrites everything with outf.
    int2* binned = (int2*)d_out;
    u32* featb = (u32*)((char*)d_out + (size_t)N_NODES * D * 2);
    float* outf = (float*)d_out;

    hipMemsetAsync(coarseCount, 0, CB * 16 * sizeof(int), stream);

    prep<<<BIN_BLKS + CF_BLKS + CW_BLKS, 256, 0, stream>>>(
        features, featb, W1, W2, W1t, W2t, row, col, values, coarseCount, binned);

    sortk<<<CB, 1024, 0, stream>>>(binned, coarseCount, rowRange, scev);

    spmm_bf16<<<(N_NODES * 64 + 255) / 256, 256, 0, stream>>>(scev, rowRange, featb, Xb);

    gemm_fused<<<(N_NODES + 127) / 128, 256, 0, stream>>>(
        (const u16*)Xb, W1t, b1, W2t, b2, outf);
}

// Round 6
// 341.559 us; speedup vs baseline: 1.2680x; 1.2680x over previous
//
#include <hip/hip_runtime.h>

#define N_NODES 100000
#define N_EDGES 1600000
#define D 128
#define CB 98       // coarse buckets of 1024 rows (ceil(100000/1024))
#define CCAP 17920  // per-bucket capacity: mean 16384, sigma 128 -> +12 sigma

typedef unsigned short u16;
typedef unsigned int u32;
typedef __attribute__((ext_vector_type(8))) short bf16x8;
typedef __attribute__((ext_vector_type(4))) float f32x4;

__device__ __forceinline__ u16 f2bf(float f) {
    u32 u = __float_as_uint(f);
    u += 0x7fffu + ((u >> 16) & 1u);  // round-to-nearest-even
    return (u16)(u >> 16);
}

// ---------------- fused front end: bin_pass | convert_feat | convert_w ----------------
// Coarse binning: 98 buckets x 1024 rows. Per 4096-edge block: LDS hist over 98
// counters, ONE returning device atomic per (block,bucket) = 38K total.
// coarseCount padded to 1 counter/cacheline. Scatter: ~42 consecutive edges per
// bucket per block -> near-full-line writes (no RMW write amplification).

#define BIN_BLKS 391  // ceil(E/4096)
#define CF_BLKS 6250  // N*D/8/256
#define CW_BLKS 128   // 32768/256

__global__ __launch_bounds__(256) void prep(
    const float* __restrict__ features, u32* __restrict__ featb,
    const float* __restrict__ W1, const float* __restrict__ W2,
    u16* __restrict__ W1t, u16* __restrict__ W2t,
    const int* __restrict__ row, const int* __restrict__ col,
    const float* __restrict__ val,
    int* __restrict__ coarseCount, int2* __restrict__ binned) {
    __shared__ int h[CB];
    __shared__ int lb[CB];
    int bid = blockIdx.x;
    int t = threadIdx.x;

    if (bid >= BIN_BLKS) {
        int cid = bid - BIN_BLKS;
        if (cid < CF_BLKS) {
            // features fp32 [N,128] -> bf16 packed (word j = cols {2j,2j+1})
            int idx = cid * 256 + t;  // [0, N*D/8)
            const float4* f4 = (const float4*)features;
            float4 a = f4[idx * 2], b = f4[idx * 2 + 1];
            uint4 o;
            o.x = (u32)f2bf(a.x) | ((u32)f2bf(a.y) << 16);
            o.y = (u32)f2bf(a.z) | ((u32)f2bf(a.w) << 16);
            o.z = (u32)f2bf(b.x) | ((u32)f2bf(b.y) << 16);
            o.w = (u32)f2bf(b.z) | ((u32)f2bf(b.w) << 16);
            ((uint4*)featb)[idx] = o;
        } else {
            // W[k][n] fp32 -> Wt[n][k] bf16, both 128x128
            int flat = (cid - CF_BLKS) * 256 + t;  // [0, 32768)
            int m = flat >> 14;
            int idx = flat & 16383;
            int n = idx & 127;
            int k = idx >> 7;
            const float* src = m ? W2 : W1;
            u16* dst = m ? W2t : W1t;
            dst[n * 128 + k] = f2bf(src[k * 128 + n]);
        }
        return;
    }

    // bin_pass: append edges into coarse buckets; pack row-local (10b) into
    // col's high bits (col < 2^17)
    if (t < CB) h[t] = 0;
    __syncthreads();
    int base = bid * 4096;
    int r[16];
#pragma unroll
    for (int i = 0; i < 16; ++i) {
        int e = base + i * 256 + t;
        r[i] = (e < N_EDGES) ? row[e] : -1;
        if (r[i] >= 0) atomicAdd(&h[r[i] >> 10], 1);
    }
    __syncthreads();
    if (t < CB) {
        int c = h[t];
        lb[t] = c ? atomicAdd(&coarseCount[t * 16], c) : 0;  // padded: 1/line
        h[t] = 0;                                            // reuse as cursor
    }
    __syncthreads();
#pragma unroll
    for (int i = 0; i < 16; ++i) {
        if (r[i] < 0) continue;
        int e = base + i * 256 + t;
        int cb = r[i] >> 10;
        int pos = cb * CCAP + lb[cb] + atomicAdd(&h[cb], 1);
        int2 ev;
        ev.x = col[e] | ((r[i] & 1023) << 17);
        ev.y = __float_as_int(val[e]);
        binned[pos] = ev;
    }
}

// ---------------- sortk: one 1024-thread block per coarse bucket ----------------
// LDS hist over 1024 row-locals -> shuffle-hierarchical exclusive scan ->
// rowRange (absolute positions into the PADDED per-bucket scev window) ->
// scatter binned -> row-sorted scev within the bucket's own ~140KB window.

__global__ __launch_bounds__(1024) void sortk(const int2* __restrict__ binned,
                                              const int* __restrict__ coarseCount,
                                              int2* __restrict__ rowRange,
                                              int2* __restrict__ scev) {
    __shared__ int h[1024];
    __shared__ int cur[1024];
    __shared__ int wsum[16];
    __shared__ int wbase[16];
    int b = blockIdx.x, t = threadIdx.x;
    int lane = t & 63, wv = t >> 6;
    int row0 = b << 10;
    int lo = b * CCAP;
    int cnt = coarseCount[b * 16];

    h[t] = 0;
    __syncthreads();
    for (int i = t; i < cnt; i += 1024)
        atomicAdd(&h[((u32)binned[lo + i].x) >> 17], 1);
    __syncthreads();

    int c = h[t];
    int x = c;  // inclusive scan within wave
#pragma unroll
    for (int d = 1; d < 64; d <<= 1) {
        int y = __shfl_up(x, d);
        if (lane >= d) x += y;
    }
    if (lane == 63) wsum[wv] = x;
    __syncthreads();
    if (t < 16) {
        int s = wsum[t], sx = s;
#pragma unroll
        for (int d = 1; d < 16; d <<= 1) {
            int y = __shfl_up(sx, d);
            if (lane >= d) sx += y;
        }
        wbase[t] = sx - s;  // exclusive base per wave
    }
    __syncthreads();
    int start = lo + wbase[wv] + (x - c);  // absolute exclusive prefix
    if (row0 + t < N_NODES) rowRange[row0 + t] = make_int2(start, start + c);
    cur[t] = start;
    __syncthreads();

    for (int i = t; i < cnt; i += 1024) {
        int2 ev = binned[lo + i];
        int rl = ((u32)ev.x) >> 17;
        int pos = atomicAdd(&cur[rl], 1);
        scev[pos] = make_int2(ev.x & 0x1FFFF, ev.y);
    }
}

// ---------------- SpMM (bf16 gather): one wave per row ----------------
// Xb[r] = bf16( featb[r] + sum_j v_j * featb[col_j] )
// wid wave-uniform via readfirstlane -> rowRange/scev stay scalar (e-batches
// live in SGPRs); clamped 16-deep batches (dup slots hit L1).
// 2-deep pipeline FORCED with sched_barrier(0): issue the next batch's 16
// gathers, fence, then consume the previous batch -> >=16 loads stay in
// flight through every consume phase (no vmcnt-drain-to-0 sawtooth).
// ROUND-5 FIX: launch_bounds (256,6) not (256,8). The 8-waves pin capped
// VGPR at 64; the pipeline needs ~58-70 live regs and the fences extend
// liveness -> allocator spilled a whole p-buffer to scratch (round 4:
// VGPR_Count=32, WRITE_SIZE 25->739MB, spmm 66->236us). Cap ~84 fits it.
// Round-2 measured only ~65% occupancy at VGPR 24, so 6-7 waves/SIMD
// costs ~nothing in TLP. Round-4's spill version still sustained 5.16TB/s
// L2-miss traffic -> the memory system has >=1.4x headroom over round-2's
// 3.7TB/s; this build targets it without the scratch.

__global__ __launch_bounds__(256, 6) void spmm_bf16(
    const int2* __restrict__ scev, const int2* __restrict__ rowRange,
    const u32* __restrict__ featb, u32* __restrict__ Xb) {
    int wid0 = (blockIdx.x * blockDim.x + threadIdx.x) >> 6;
    int wid = __builtin_amdgcn_readfirstlane(wid0);
    int lane = threadIdx.x & 63;
    if (wid >= N_NODES) return;
    int2 rr = rowRange[wid];
    int j = rr.x, end = rr.y;
    u32 self = featb[wid * 64 + lane];
    float ax0 = __uint_as_float(self << 16);
    float ay0 = __uint_as_float(self & 0xffff0000u);
    float ax1 = 0.f, ay1 = 0.f;

    if (j < end) {
        int2 eA[16], eB[16];
        u32 pA[16], pB[16];

#define LOADE(E, JB)                                                     \
    _Pragma("unroll") for (int u = 0; u < 16; ++u) {                     \
        int idx = (JB) + u;                                              \
        int c = (idx < end) ? idx : (end - 1); /* uniform: stays SGPR */ \
        E[u] = scev[c];                                                  \
        if (idx >= end) E[u].y = 0; /* inactive slot contributes 0 */    \
    }

#define GATH(P, E)                                                       \
    _Pragma("unroll") for (int u = 0; u < 16; ++u)                       \
        P[u] = featb[E[u].x * 64 + lane];

#define CONS(E, P)                                                       \
    _Pragma("unroll") for (int u = 0; u < 16; ++u) {                     \
        float v = __int_as_float(E[u].y);                                \
        float lo = __uint_as_float(P[u] << 16);                          \
        float hi = __uint_as_float(P[u] & 0xffff0000u);                  \
        if (u & 1) { ax1 += v * lo; ay1 += v * hi; }                     \
        else       { ax0 += v * lo; ay0 += v * hi; }                     \
    }

#define SB __builtin_amdgcn_sched_barrier(0)

        int nb = (end - j + 15) >> 4;
        LOADE(eA, j);
        GATH(pA, eA);
        int jb = j + 16;
        int b = 1;
        while (b + 1 < nb) {
            LOADE(eB, jb);
            GATH(pB, eB);
            SB;  // pB gathers must issue before pA consume
            CONS(eA, pA);
            LOADE(eA, jb + 16);
            GATH(pA, eA);
            SB;  // pA' gathers must issue before pB consume
            CONS(eB, pB);
            jb += 32;
            b += 2;
        }
        if (b < nb) {
            LOADE(eB, jb);
            GATH(pB, eB);
            SB;
            CONS(eA, pA);
            CONS(eB, pB);
        } else {
            CONS(eA, pA);
        }
#undef LOADE
#undef GATH
#undef CONS
#undef SB
    }

    float accx = ax0 + ax1;
    float accy = ay0 + ay1;
    Xb[wid * 64 + lane] = (u32)f2bf(accx) | ((u32)f2bf(accy) << 16);
}

// ---------------- fused MFMA GEMM: out = relu(X@W1+b1)@W2 + b2 ----------------
// Stage 1: W1 staged in LDS, MFMA -> bias+ReLU. H never touches HBM:
// C-fragments packed as bf16 u32-pairs into a TRANSPOSED LDS tile Ht[col][row]
// aliased over Ws (W1 dead after stage 1; barrier-separated). Stage-2
// A-fragments read Ht[k][l16] conflict-free; B-fragments stream straight from
// global W2t (32 KB, L2-resident). Saves the 51.2 MB Hb round-trip + a launch.

__global__ __launch_bounds__(256, 2) void gemm_fused(
    const u16* __restrict__ Xb, const u16* __restrict__ W1t,
    const float* __restrict__ b1, const u16* __restrict__ W2t,
    const float* __restrict__ b2, float* __restrict__ outf) {
    __shared__ u16 Ws[128][136];               // 34816 B; stage 2 aliases Ht over it
    u16(*Ht)[130] = (u16(*)[130]) & Ws[0][0];  // 128x130 = 33280 B <= 34816

    int t = threadIdx.x;
    {
        const uint4* wsrc = (const uint4*)W1t;
#pragma unroll
        for (int i = 0; i < 8; ++i) {
            int f = t + 256 * i;
            *(uint4*)&Ws[f >> 4][(f & 15) << 3] = wsrc[f];
        }
    }
    __syncthreads();

    int w = t >> 6, lane = t & 63;
    int quad = lane >> 4, l16 = lane & 15;
    int row0 = blockIdx.x * 128 + w * 32;

    f32x4 acc[2][8];
#pragma unroll
    for (int rt = 0; rt < 2; ++rt)
#pragma unroll
        for (int ct = 0; ct < 8; ++ct) acc[rt][ct] = (f32x4){0.f, 0.f, 0.f, 0.f};

    int ra = row0 + l16;
    int rb = row0 + 16 + l16;
    if (ra > N_NODES - 1) ra = N_NODES - 1;
    if (rb > N_NODES - 1) rb = N_NODES - 1;
    const u16* pa = Xb + (size_t)ra * D + quad * 8;
    const u16* pb = Xb + (size_t)rb * D + quad * 8;

#pragma unroll
    for (int kb = 0; kb < 128; kb += 32) {
        bf16x8 a0 = *(const bf16x8*)(pa + kb);
        bf16x8 a1 = *(const bf16x8*)(pb + kb);
#pragma unroll
        for (int ct = 0; ct < 8; ++ct) {
            bf16x8 b = *(const bf16x8*)&Ws[ct * 16 + l16][kb + quad * 8];
            acc[0][ct] = __builtin_amdgcn_mfma_f32_16x16x32_bf16(a0, b, acc[0][ct], 0, 0, 0);
            acc[1][ct] = __builtin_amdgcn_mfma_f32_16x16x32_bf16(a1, b, acc[1][ct], 0, 0, 0);
        }
    }

    float bv1[8];
#pragma unroll
    for (int ct = 0; ct < 8; ++ct) bv1[ct] = b1[ct * 16 + l16];

    __syncthreads();  // all W1 reads complete before Ht overwrites Ws

    int hbase = w * 32;  // this wave's local row base
#pragma unroll
    for (int rt = 0; rt < 2; ++rt) {
#pragma unroll
        for (int ct = 0; ct < 8; ++ct) {
            float v0 = fmaxf(acc[rt][ct][0] + bv1[ct], 0.f);
            float v1 = fmaxf(acc[rt][ct][1] + bv1[ct], 0.f);
            float v2 = fmaxf(acc[rt][ct][2] + bv1[ct], 0.f);
            float v3 = fmaxf(acc[rt][ct][3] + bv1[ct], 0.f);
            u16* dst = &Ht[ct * 16 + l16][hbase + rt * 16 + quad * 4];
            ((u32*)dst)[0] = (u32)f2bf(v0) | ((u32)f2bf(v1) << 16);
            ((u32*)dst)[1] = (u32)f2bf(v2) | ((u32)f2bf(v3) << 16);
        }
    }
    __syncthreads();

    f32x4 acc2[2][8];
#pragma unroll
    for (int rt = 0; rt < 2; ++rt)
#pragma unroll
        for (int ct = 0; ct < 8; ++ct) acc2[rt][ct] = (f32x4){0.f, 0.f, 0.f, 0.f};

#pragma unroll
    for (int kb = 0; kb < 128; kb += 32) {
        bf16x8 a0, a1;
#pragma unroll
        for (int i = 0; i < 8; ++i) {
            a0[i] = (short)Ht[kb + quad * 8 + i][hbase + l16];
            a1[i] = (short)Ht[kb + quad * 8 + i][hbase + 16 + l16];
        }
#pragma unroll
        for (int ct = 0; ct < 8; ++ct) {
            bf16x8 b = *(const bf16x8*)(W2t + (size_t)(ct * 16 + l16) * D + kb + quad * 8);
            acc2[0][ct] = __builtin_amdgcn_mfma_f32_16x16x32_bf16(a0, b, acc2[0][ct], 0, 0, 0);
            acc2[1][ct] = __builtin_amdgcn_mfma_f32_16x16x32_bf16(a1, b, acc2[1][ct], 0, 0, 0);
        }
    }

    float bv2[8];
#pragma unroll
    for (int ct = 0; ct < 8; ++ct) bv2[ct] = b2[ct * 16 + l16];

#pragma unroll
    for (int rt = 0; rt < 2; ++rt) {
#pragma unroll
        for (int r = 0; r < 4; ++r) {
            int row = row0 + rt * 16 + quad * 4 + r;
            if (row >= N_NODES) continue;
#pragma unroll
            for (int ct = 0; ct < 8; ++ct) {
                outf[(size_t)row * D + ct * 16 + l16] = acc2[rt][ct][r] + bv2[ct];
            }
        }
    }
}

extern "C" void kernel_launch(void* const* d_in, const int* in_sizes, int n_in,
                              void* d_out, int out_size, void* d_ws, size_t ws_size,
                              hipStream_t stream) {
    const int* indices = (const int*)d_in[0];      // [2, E]
    const float* values = (const float*)d_in[1];   // [E]
    const float* features = (const float*)d_in[2]; // [N, 128]
    const float* W1 = (const float*)d_in[3];
    const float* b1 = (const float*)d_in[4];
    const float* W2 = (const float*)d_in[5];
    const float* b2 = (const float*)d_in[6];

    const int* row = indices;
    const int* col = indices + N_EDGES;

    // ws (ints): coarseCount[CB*16] pad | rowRange[N] int2 | scev[CB*CCAP] int2 |
    //            Xb[N*64] u32 | W1t/W2t u16     total ~40.5 MB
    int* wsI = (int*)d_ws;
    int* coarseCount = wsI;                        // CB*16 = 1568 ints (1/line)
    int2* rowRange = (int2*)(wsI + 1600);          // 800 KB
    int2* scev = (int2*)(wsI + 1600 + 2 * N_NODES);  // 14.05 MB
    u32* Xb = (u32*)(wsI + 1600 + 2 * N_NODES + 2 * CB * CCAP);  // 25.6 MB, 16B-aligned
    u16* W1t = (u16*)(Xb + (size_t)N_NODES * 64);
    u16* W2t = W1t + 16384;

    // d_out: binned[CB*CCAP] int2 (14.05 MB, dead after sortk) lower part;
    // featb (bf16 features, 25.6 MB, dead after spmm) upper half;
    // gemm_fused overwrites everything with outf.
    int2* binned = (int2*)d_out;
    u32* featb = (u32*)((char*)d_out + (size_t)N_NODES * D * 2);
    float* outf = (float*)d_out;

    hipMemsetAsync(coarseCount, 0, CB * 16 * sizeof(int), stream);

    prep<<<BIN_BLKS + CF_BLKS + CW_BLKS, 256, 0, stream>>>(
        features, featb, W1, W2, W1t, W2t, row, col, values, coarseCount, binned);

    sortk<<<CB, 1024, 0, stream>>>(binned, coarseCount, rowRange, scev);

    spmm_bf16<<<(N_NODES * 64 + 255) / 256, 256, 0, stream>>>(scev, rowRange, featb, Xb);

    gemm_fused<<<(N_NODES + 127) / 128, 256, 0, stream>>>(
        (const u16*)Xb, W1t, b1, W2t, b2, outf);
}

// Round 7
// 284.076 us; speedup vs baseline: 1.5246x; 1.2024x over previous
//
#include <hip/hip_runtime.h>

#define N_NODES 100000
#define N_EDGES 1600000
#define D 128
#define CB 98       // coarse buckets of 1024 rows (ceil(100000/1024))
#define CCAP 17920  // per-bucket capacity: mean 16384, sigma 128 -> +12 sigma

typedef unsigned short u16;
typedef unsigned int u32;
typedef __attribute__((ext_vector_type(8))) short bf16x8;
typedef __attribute__((ext_vector_type(4))) float f32x4;

__device__ __forceinline__ u16 f2bf(float f) {
    u32 u = __float_as_uint(f);
    u += 0x7fffu + ((u >> 16) & 1u);  // round-to-nearest-even
    return (u16)(u >> 16);
}

// ---------------- fused front end: bin_pass | convert_feat | convert_w ----------------
// Coarse binning: 98 buckets x 1024 rows. Per 4096-edge block: LDS hist over 98
// counters, ONE returning device atomic per (block,bucket) = 38K total.
// coarseCount padded to 1 counter/cacheline. Scatter: ~42 consecutive edges per
// bucket per block -> near-full-line writes (no RMW write amplification).

#define BIN_BLKS 391  // ceil(E/4096)
#define CF_BLKS 6250  // N*D/8/256
#define CW_BLKS 128   // 32768/256

__global__ __launch_bounds__(256) void prep(
    const float* __restrict__ features, u32* __restrict__ featb,
    const float* __restrict__ W1, const float* __restrict__ W2,
    u16* __restrict__ W1t, u16* __restrict__ W2t,
    const int* __restrict__ row, const int* __restrict__ col,
    const float* __restrict__ val,
    int* __restrict__ coarseCount, int2* __restrict__ binned) {
    __shared__ int h[CB];
    __shared__ int lb[CB];
    int bid = blockIdx.x;
    int t = threadIdx.x;

    if (bid >= BIN_BLKS) {
        int cid = bid - BIN_BLKS;
        if (cid < CF_BLKS) {
            // features fp32 [N,128] -> bf16 packed (word j = cols {2j,2j+1})
            int idx = cid * 256 + t;  // [0, N*D/8)
            const float4* f4 = (const float4*)features;
            float4 a = f4[idx * 2], b = f4[idx * 2 + 1];
            uint4 o;
            o.x = (u32)f2bf(a.x) | ((u32)f2bf(a.y) << 16);
            o.y = (u32)f2bf(a.z) | ((u32)f2bf(a.w) << 16);
            o.z = (u32)f2bf(b.x) | ((u32)f2bf(b.y) << 16);
            o.w = (u32)f2bf(b.z) | ((u32)f2bf(b.w) << 16);
            ((uint4*)featb)[idx] = o;
        } else {
            // W[k][n] fp32 -> Wt[n][k] bf16, both 128x128
            int flat = (cid - CF_BLKS) * 256 + t;  // [0, 32768)
            int m = flat >> 14;
            int idx = flat & 16383;
            int n = idx & 127;
            int k = idx >> 7;
            const float* src = m ? W2 : W1;
            u16* dst = m ? W2t : W1t;
            dst[n * 128 + k] = f2bf(src[k * 128 + n]);
        }
        return;
    }

    // bin_pass: append edges into coarse buckets; pack row-local (10b) into
    // col's high bits (col < 2^17)
    if (t < CB) h[t] = 0;
    __syncthreads();
    int base = bid * 4096;
    int r[16];
#pragma unroll
    for (int i = 0; i < 16; ++i) {
        int e = base + i * 256 + t;
        r[i] = (e < N_EDGES) ? row[e] : -1;
        if (r[i] >= 0) atomicAdd(&h[r[i] >> 10], 1);
    }
    __syncthreads();
    if (t < CB) {
        int c = h[t];
        lb[t] = c ? atomicAdd(&coarseCount[t * 16], c) : 0;  // padded: 1/line
        h[t] = 0;                                            // reuse as cursor
    }
    __syncthreads();
#pragma unroll
    for (int i = 0; i < 16; ++i) {
        if (r[i] < 0) continue;
        int e = base + i * 256 + t;
        int cb = r[i] >> 10;
        int pos = cb * CCAP + lb[cb] + atomicAdd(&h[cb], 1);
        int2 ev;
        ev.x = col[e] | ((r[i] & 1023) << 17);
        ev.y = __float_as_int(val[e]);
        binned[pos] = ev;
    }
}

// ---------------- sortk: one 1024-thread block per coarse bucket ----------------
// LDS hist over 1024 row-locals -> shuffle-hierarchical exclusive scan ->
// rowRange (absolute positions into the PADDED per-bucket scev window) ->
// scatter binned -> row-sorted scev within the bucket's own ~140KB window.

__global__ __launch_bounds__(1024) void sortk(const int2* __restrict__ binned,
                                              const int* __restrict__ coarseCount,
                                              int2* __restrict__ rowRange,
                                              int2* __restrict__ scev) {
    __shared__ int h[1024];
    __shared__ int cur[1024];
    __shared__ int wsum[16];
    __shared__ int wbase[16];
    int b = blockIdx.x, t = threadIdx.x;
    int lane = t & 63, wv = t >> 6;
    int row0 = b << 10;
    int lo = b * CCAP;
    int cnt = coarseCount[b * 16];

    h[t] = 0;
    __syncthreads();
    for (int i = t; i < cnt; i += 1024)
        atomicAdd(&h[((u32)binned[lo + i].x) >> 17], 1);
    __syncthreads();

    int c = h[t];
    int x = c;  // inclusive scan within wave
#pragma unroll
    for (int d = 1; d < 64; d <<= 1) {
        int y = __shfl_up(x, d);
        if (lane >= d) x += y;
    }
    if (lane == 63) wsum[wv] = x;
    __syncthreads();
    if (t < 16) {
        int s = wsum[t], sx = s;
#pragma unroll
        for (int d = 1; d < 16; d <<= 1) {
            int y = __shfl_up(sx, d);
            if (lane >= d) sx += y;
        }
        wbase[t] = sx - s;  // exclusive base per wave
    }
    __syncthreads();
    int start = lo + wbase[wv] + (x - c);  // absolute exclusive prefix
    if (row0 + t < N_NODES) rowRange[row0 + t] = make_int2(start, start + c);
    cur[t] = start;
    __syncthreads();

    for (int i = t; i < cnt; i += 1024) {
        int2 ev = binned[lo + i];
        int rl = ((u32)ev.x) >> 17;
        int pos = atomicAdd(&cur[rl], 1);
        scev[pos] = make_int2(ev.x & 0x1FFFF, ev.y);
    }
}

// ---------------- SpMM (bf16 gather): one wave per row, LDS-staged pipeline ----
// Xb[r] = bf16( featb[r] + sum_j v_j * featb[col_j] )
// wid wave-uniform via readfirstlane -> rowRange/scev stay scalar.
// ROUND-6 PIVOT: hold the 2-deep pipeline in LDS via global_load_lds, not
// VGPRs. Each gather = 64 lanes x 4B = one 256B featb row = exactly the
// instruction's shape (per-lane global src, wave-uniform LDS dst + lane*4).
// Per wave: two 4KB slots (16 gathers each), double-buffered; issue batch
// b+1 into B, s_waitcnt vmcnt(16) (counted, never 0 in steady state),
// consume A via conflict-free ds_read_b32 (base+lane*4). Gather data never
// touches a VGPR -> nothing to spill (rounds 4/5: VGPR-resident pipeline
// spilled, WRITE_SIZE 25->739/417MB). Edge values ride in uniform SGPRs.
// vmcnt(16) is safe even if scev loads vectorize (wait turns conservative,
// not incorrect); same-buffer write-after-read is program-ordered.
// LDS 4 waves x 8KB = 32KB/block -> 5 blocks/CU (~62% occ, = round-2's
// measured 65%, so no TLP loss) while >=16 loads/wave stay in flight
// through every consume phase.

__global__ __launch_bounds__(256) void spmm_bf16(
    const int2* __restrict__ scev, const int2* __restrict__ rowRange,
    const u32* __restrict__ featb, u32* __restrict__ Xb) {
    __shared__ u32 stage[4][2][16][64];  // 32 KB: [wave][buf][slot][lane]
    int tid = threadIdx.x;
    int wv = tid >> 6, lane = tid & 63;
    int wid = __builtin_amdgcn_readfirstlane((blockIdx.x * blockDim.x + tid) >> 6);
    if (wid >= N_NODES) return;
    int2 rr = rowRange[wid];
    int j = rr.x, end = rr.y;
    u32 self = featb[wid * 64 + lane];
    float ax0 = __uint_as_float(self << 16);
    float ay0 = __uint_as_float(self & 0xffff0000u);
    float ax1 = 0.f, ay1 = 0.f;

    if (j < end) {
        u32(*bufA)[64] = stage[wv][0];
        u32(*bufB)[64] = stage[wv][1];
        int VA[16], VB[16];

// issue one batch: per slot u, scalar-load edge, keep value (uniform SGPR),
// fire global_load_lds (per-lane src featb[col*64+lane] -> slot base+lane*4)
#define LOADG(V, BUF, JB)                                                     \
    _Pragma("unroll") for (int u = 0; u < 16; ++u) {                          \
        int idx = (JB) + u;                                                   \
        int c = (idx < end) ? idx : (end - 1); /* uniform: stays scalar */    \
        int2 ev = scev[c];                                                    \
        if (idx >= end) ev.y = 0; /* inactive slot contributes 0 */           \
        V[u] = ev.y;                                                          \
        __builtin_amdgcn_global_load_lds(                                     \
            (const __attribute__((address_space(1))) u32*)(featb +            \
                                                           ev.x * 64 + lane), \
            (__attribute__((address_space(3))) u32*)&BUF[u][0], 4, 0, 0);     \
    }

#define CONS(V, BUF)                                                          \
    _Pragma("unroll") for (int u = 0; u < 16; ++u) {                          \
        float v = __int_as_float(V[u]);                                       \
        u32 p = BUF[u][lane];                                                 \
        float lo = __uint_as_float(p << 16);                                  \
        float hi = __uint_as_float(p & 0xffff0000u);                          \
        if (u & 1) { ax1 += v * lo; ay1 += v * hi; }                          \
        else       { ax0 += v * lo; ay0 += v * hi; }                          \
    }

#define WAIT16 asm volatile("s_waitcnt vmcnt(16)" ::: "memory")
#define WAIT0 asm volatile("s_waitcnt vmcnt(0)" ::: "memory")

        int nb = (end - j + 15) >> 4;
        LOADG(VA, bufA, j);
        int jb = j + 16;
        int b = 1;
        while (b + 1 < nb) {
            LOADG(VB, bufB, jb);
            WAIT16;  // batch b-1 (bufA) landed; bufB's 16 stay in flight
            CONS(VA, bufA);
            LOADG(VA, bufA, jb + 16);
            WAIT16;  // bufB landed; new bufA in flight
            CONS(VB, bufB);
            jb += 32;
            b += 2;
        }
        if (b < nb) {
            LOADG(VB, bufB, jb);
            WAIT16;
            CONS(VA, bufA);
            WAIT0;
            CONS(VB, bufB);
        } else {
            WAIT0;
            CONS(VA, bufA);
        }
#undef LOADG
#undef CONS
#undef WAIT16
#undef WAIT0
    }

    float accx = ax0 + ax1;
    float accy = ay0 + ay1;
    Xb[wid * 64 + lane] = (u32)f2bf(accx) | ((u32)f2bf(accy) << 16);
}

// ---------------- fused MFMA GEMM: out = relu(X@W1+b1)@W2 + b2 ----------------
// Stage 1: W1 staged in LDS, MFMA -> bias+ReLU. H never touches HBM:
// C-fragments packed as bf16 u32-pairs into a TRANSPOSED LDS tile Ht[col][row]
// aliased over Ws (W1 dead after stage 1; barrier-separated). Stage-2
// A-fragments read Ht[k][l16] conflict-free; B-fragments stream straight from
// global W2t (32 KB, L2-resident). Saves the 51.2 MB Hb round-trip + a launch.

__global__ __launch_bounds__(256, 2) void gemm_fused(
    const u16* __restrict__ Xb, const u16* __restrict__ W1t,
    const float* __restrict__ b1, const u16* __restrict__ W2t,
    const float* __restrict__ b2, float* __restrict__ outf) {
    __shared__ u16 Ws[128][136];               // 34816 B; stage 2 aliases Ht over it
    u16(*Ht)[130] = (u16(*)[130]) & Ws[0][0];  // 128x130 = 33280 B <= 34816

    int t = threadIdx.x;
    {
        const uint4* wsrc = (const uint4*)W1t;
#pragma unroll
        for (int i = 0; i < 8; ++i) {
            int f = t + 256 * i;
            *(uint4*)&Ws[f >> 4][(f & 15) << 3] = wsrc[f];
        }
    }
    __syncthreads();

    int w = t >> 6, lane = t & 63;
    int quad = lane >> 4, l16 = lane & 15;
    int row0 = blockIdx.x * 128 + w * 32;

    f32x4 acc[2][8];
#pragma unroll
    for (int rt = 0; rt < 2; ++rt)
#pragma unroll
        for (int ct = 0; ct < 8; ++ct) acc[rt][ct] = (f32x4){0.f, 0.f, 0.f, 0.f};

    int ra = row0 + l16;
    int rb = row0 + 16 + l16;
    if (ra > N_NODES - 1) ra = N_NODES - 1;
    if (rb > N_NODES - 1) rb = N_NODES - 1;
    const u16* pa = Xb + (size_t)ra * D + quad * 8;
    const u16* pb = Xb + (size_t)rb * D + quad * 8;

#pragma unroll
    for (int kb = 0; kb < 128; kb += 32) {
        bf16x8 a0 = *(const bf16x8*)(pa + kb);
        bf16x8 a1 = *(const bf16x8*)(pb + kb);
#pragma unroll
        for (int ct = 0; ct < 8; ++ct) {
            bf16x8 b = *(const bf16x8*)&Ws[ct * 16 + l16][kb + quad * 8];
            acc[0][ct] = __builtin_amdgcn_mfma_f32_16x16x32_bf16(a0, b, acc[0][ct], 0, 0, 0);
            acc[1][ct] = __builtin_amdgcn_mfma_f32_16x16x32_bf16(a1, b, acc[1][ct], 0, 0, 0);
        }
    }

    float bv1[8];
#pragma unroll
    for (int ct = 0; ct < 8; ++ct) bv1[ct] = b1[ct * 16 + l16];

    __syncthreads();  // all W1 reads complete before Ht overwrites Ws

    int hbase = w * 32;  // this wave's local row base
#pragma unroll
    for (int rt = 0; rt < 2; ++rt) {
#pragma unroll
        for (int ct = 0; ct < 8; ++ct) {
            float v0 = fmaxf(acc[rt][ct][0] + bv1[ct], 0.f);
            float v1 = fmaxf(acc[rt][ct][1] + bv1[ct], 0.f);
            float v2 = fmaxf(acc[rt][ct][2] + bv1[ct], 0.f);
            float v3 = fmaxf(acc[rt][ct][3] + bv1[ct], 0.f);
            u16* dst = &Ht[ct * 16 + l16][hbase + rt * 16 + quad * 4];
            ((u32*)dst)[0] = (u32)f2bf(v0) | ((u32)f2bf(v1) << 16);
            ((u32*)dst)[1] = (u32)f2bf(v2) | ((u32)f2bf(v3) << 16);
        }
    }
    __syncthreads();

    f32x4 acc2[2][8];
#pragma unroll
    for (int rt = 0; rt < 2; ++rt)
#pragma unroll
        for (int ct = 0; ct < 8; ++ct) acc2[rt][ct] = (f32x4){0.f, 0.f, 0.f, 0.f};

#pragma unroll
    for (int kb = 0; kb < 128; kb += 32) {
        bf16x8 a0, a1;
#pragma unroll
        for (int i = 0; i < 8; ++i) {
            a0[i] = (short)Ht[kb + quad * 8 + i][hbase + l16];
            a1[i] = (short)Ht[kb + quad * 8 + i][hbase + 16 + l16];
        }
#pragma unroll
        for (int ct = 0; ct < 8; ++ct) {
            bf16x8 b = *(const bf16x8*)(W2t + (size_t)(ct * 16 + l16) * D + kb + quad * 8);
            acc2[0][ct] = __builtin_amdgcn_mfma_f32_16x16x32_bf16(a0, b, acc2[0][ct], 0, 0, 0);
            acc2[1][ct] = __builtin_amdgcn_mfma_f32_16x16x32_bf16(a1, b, acc2[1][ct], 0, 0, 0);
        }
    }

    float bv2[8];
#pragma unroll
    for (int ct = 0; ct < 8; ++ct) bv2[ct] = b2[ct * 16 + l16];

#pragma unroll
    for (int rt = 0; rt < 2; ++rt) {
#pragma unroll
        for (int r = 0; r < 4; ++r) {
            int row = row0 + rt * 16 + quad * 4 + r;
            if (row >= N_NODES) continue;
#pragma unroll
            for (int ct = 0; ct < 8; ++ct) {
                outf[(size_t)row * D + ct * 16 + l16] = acc2[rt][ct][r] + bv2[ct];
            }
        }
    }
}

extern "C" void kernel_launch(void* const* d_in, const int* in_sizes, int n_in,
                              void* d_out, int out_size, void* d_ws, size_t ws_size,
                              hipStream_t stream) {
    const int* indices = (const int*)d_in[0];      // [2, E]
    const float* values = (const float*)d_in[1];   // [E]
    const float* features = (const float*)d_in[2]; // [N, 128]
    const float* W1 = (const float*)d_in[3];
    const float* b1 = (const float*)d_in[4];
    const float* W2 = (const float*)d_in[5];
    const float* b2 = (const float*)d_in[6];

    const int* row = indices;
    const int* col = indices + N_EDGES;

    // ws (ints): coarseCount[CB*16] pad | rowRange[N] int2 | scev[CB*CCAP] int2 |
    //            Xb[N*64] u32 | W1t/W2t u16     total ~40.5 MB
    int* wsI = (int*)d_ws;
    int* coarseCount = wsI;                        // CB*16 = 1568 ints (1/line)
    int2* rowRange = (int2*)(wsI + 1600);          // 800 KB
    int2* scev = (int2*)(wsI + 1600 + 2 * N_NODES);  // 14.05 MB
    u32* Xb = (u32*)(wsI + 1600 + 2 * N_NODES + 2 * CB * CCAP);  // 25.6 MB, 16B-aligned
    u16* W1t = (u16*)(Xb + (size_t)N_NODES * 64);
    u16* W2t = W1t + 16384;

    // d_out: binned[CB*CCAP] int2 (14.05 MB, dead after sortk) lower part;
    // featb (bf16 features, 25.6 MB, dead after spmm) upper half;
    // gemm_fused overwrites everything with outf.
    int2* binned = (int2*)d_out;
    u32* featb = (u32*)((char*)d_out + (size_t)N_NODES * D * 2);
    float* outf = (float*)d_out;

    hipMemsetAsync(coarseCount, 0, CB * 16 * sizeof(int), stream);

    prep<<<BIN_BLKS + CF_BLKS + CW_BLKS, 256, 0, stream>>>(
        features, featb, W1, W2, W1t, W2t, row, col, values, coarseCount, binned);

    sortk<<<CB, 1024, 0, stream>>>(binned, coarseCount, rowRange, scev);

    spmm_bf16<<<(N_NODES * 64 + 255) / 256, 256, 0, stream>>>(scev, rowRange, featb, Xb);

    gemm_fused<<<(N_NODES + 127) / 128, 256, 0, stream>>>(
        (const u16*)Xb, W1t, b1, W2t, b2, outf);
}

// Round 8
// 256.253 us; speedup vs baseline: 1.6901x; 1.1086x over previous
//
#include <hip/hip_runtime.h>

#define N_NODES 100000
#define N_EDGES 1600000
#define D 128
#define CB 98       // coarse buckets of 1024 rows (ceil(100000/1024))
#define CCAP 17920  // per-bucket capacity: mean 16384, sigma 128 -> +12 sigma

typedef unsigned short u16;
typedef unsigned int u32;
typedef __attribute__((ext_vector_type(8))) short bf16x8;
typedef __attribute__((ext_vector_type(4))) float f32x4;

__device__ __forceinline__ u16 f2bf(float f) {
    u32 u = __float_as_uint(f);
    u += 0x7fffu + ((u >> 16) & 1u);  // round-to-nearest-even
    return (u16)(u >> 16);
}

// ---------------- fused front end: bin_pass | convert_feat | convert_w ----------------
// Coarse binning: 98 buckets x 1024 rows. Per 4096-edge block: LDS hist over 98
// counters, ONE returning device atomic per (block,bucket) = 38K total.
// coarseCount padded to 1 counter/cacheline. Scatter: ~42 consecutive edges per
// bucket per block -> near-full-line writes (no RMW write amplification).

#define BIN_BLKS 391  // ceil(E/4096)
#define CF_BLKS 6250  // N*D/8/256
#define CW_BLKS 128   // 32768/256

__global__ __launch_bounds__(256) void prep(
    const float* __restrict__ features, u32* __restrict__ featb,
    const float* __restrict__ W1, const float* __restrict__ W2,
    u16* __restrict__ W1t, u16* __restrict__ W2t,
    const int* __restrict__ row, const int* __restrict__ col,
    const float* __restrict__ val,
    int* __restrict__ coarseCount, int2* __restrict__ binned) {
    __shared__ int h[CB];
    __shared__ int lb[CB];
    int bid = blockIdx.x;
    int t = threadIdx.x;

    if (bid >= BIN_BLKS) {
        int cid = bid - BIN_BLKS;
        if (cid < CF_BLKS) {
            // features fp32 [N,128] -> bf16 packed (word j = cols {2j,2j+1})
            int idx = cid * 256 + t;  // [0, N*D/8)
            const float4* f4 = (const float4*)features;
            float4 a = f4[idx * 2], b = f4[idx * 2 + 1];
            uint4 o;
            o.x = (u32)f2bf(a.x) | ((u32)f2bf(a.y) << 16);
            o.y = (u32)f2bf(a.z) | ((u32)f2bf(a.w) << 16);
            o.z = (u32)f2bf(b.x) | ((u32)f2bf(b.y) << 16);
            o.w = (u32)f2bf(b.z) | ((u32)f2bf(b.w) << 16);
            ((uint4*)featb)[idx] = o;
        } else {
            // W[k][n] fp32 -> Wt[n][k] bf16, both 128x128
            int flat = (cid - CF_BLKS) * 256 + t;  // [0, 32768)
            int m = flat >> 14;
            int idx = flat & 16383;
            int n = idx & 127;
            int k = idx >> 7;
            const float* src = m ? W2 : W1;
            u16* dst = m ? W2t : W1t;
            dst[n * 128 + k] = f2bf(src[k * 128 + n]);
        }
        return;
    }

    // bin_pass: append edges into coarse buckets; pack row-local (10b) into
    // col's high bits (col < 2^17)
    if (t < CB) h[t] = 0;
    __syncthreads();
    int base = bid * 4096;
    int r[16];
#pragma unroll
    for (int i = 0; i < 16; ++i) {
        int e = base + i * 256 + t;
        r[i] = (e < N_EDGES) ? row[e] : -1;
        if (r[i] >= 0) atomicAdd(&h[r[i] >> 10], 1);
    }
    __syncthreads();
    if (t < CB) {
        int c = h[t];
        lb[t] = c ? atomicAdd(&coarseCount[t * 16], c) : 0;  // padded: 1/line
        h[t] = 0;                                            // reuse as cursor
    }
    __syncthreads();
#pragma unroll
    for (int i = 0; i < 16; ++i) {
        if (r[i] < 0) continue;
        int e = base + i * 256 + t;
        int cb = r[i] >> 10;
        int pos = cb * CCAP + lb[cb] + atomicAdd(&h[cb], 1);
        int2 ev;
        ev.x = col[e] | ((r[i] & 1023) << 17);
        ev.y = __float_as_int(val[e]);
        binned[pos] = ev;
    }
}

// ---------------- sortk: one 1024-thread block per coarse bucket ----------------
// LDS hist over 1024 row-locals -> shuffle-hierarchical exclusive scan ->
// rowRange (absolute positions into the PADDED per-bucket scev window) ->
// scatter binned -> row-sorted scev within the bucket's own ~140KB window.

__global__ __launch_bounds__(1024) void sortk(const int2* __restrict__ binned,
                                              const int* __restrict__ coarseCount,
                                              int2* __restrict__ rowRange,
                                              int2* __restrict__ scev) {
    __shared__ int h[1024];
    __shared__ int cur[1024];
    __shared__ int wsum[16];
    __shared__ int wbase[16];
    int b = blockIdx.x, t = threadIdx.x;
    int lane = t & 63, wv = t >> 6;
    int row0 = b << 10;
    int lo = b * CCAP;
    int cnt = coarseCount[b * 16];

    h[t] = 0;
    __syncthreads();
    for (int i = t; i < cnt; i += 1024)
        atomicAdd(&h[((u32)binned[lo + i].x) >> 17], 1);
    __syncthreads();

    int c = h[t];
    int x = c;  // inclusive scan within wave
#pragma unroll
    for (int d = 1; d < 64; d <<= 1) {
        int y = __shfl_up(x, d);
        if (lane >= d) x += y;
    }
    if (lane == 63) wsum[wv] = x;
    __syncthreads();
    if (t < 16) {
        int s = wsum[t], sx = s;
#pragma unroll
        for (int d = 1; d < 16; d <<= 1) {
            int y = __shfl_up(sx, d);
            if (lane >= d) sx += y;
        }
        wbase[t] = sx - s;  // exclusive base per wave
    }
    __syncthreads();
    int start = lo + wbase[wv] + (x - c);  // absolute exclusive prefix
    if (row0 + t < N_NODES) rowRange[row0 + t] = make_int2(start, start + c);
    cur[t] = start;
    __syncthreads();

    for (int i = t; i < cnt; i += 1024) {
        int2 ev = binned[lo + i];
        int rl = ((u32)ev.x) >> 17;
        int pos = atomicAdd(&cur[rl], 1);
        scev[pos] = make_int2(ev.x & 0x1FFFF, ev.y);
    }
}

// ---------------- SpMM (bf16 gather): one wave per row ----------------
// Xb[r] = bf16( featb[r] + sum_j v_j * featb[col_j] )
// wid wave-uniform via readfirstlane -> rowRange/scev become scalar loads.
// ROUND-7: revert to the proven round-2 shape (issue->drain->consume, no
// fences/LDS — compiler schedules it cleanly at low VGPR) with ONE change:
// clamped batch depth 16 -> 32. Serial latency rounds per row drop from
// avg ceil(deg/16)=1.55 to ceil(deg/32)=1.12 (-28%), and per-wave in-flight
// doubles during issue. Dup slots (deg<32 tail) all hit the end-1 line in
// L1 — no TCC traffic. p[32] ~= 40 VGPR, still 8 waves/SIMD; e-batch stays
// in SGPRs. Rounds 4-6 showed the fabric sustains 4.9-5.2 TB/s on this
// pattern when outstanding requests rise; this targets it with the only
// structure that hasn't spilled or lost occupancy.

__global__ __launch_bounds__(256) void spmm_bf16(
    const int2* __restrict__ scev, const int2* __restrict__ rowRange,
    const u32* __restrict__ featb, u32* __restrict__ Xb) {
    int wid0 = (blockIdx.x * blockDim.x + threadIdx.x) >> 6;
    int wid = __builtin_amdgcn_readfirstlane(wid0);
    int lane = threadIdx.x & 63;
    if (wid >= N_NODES) return;
    int2 rr = rowRange[wid];
    int j = rr.x, end = rr.y;
    u32 self = featb[wid * 64 + lane];
    float ax0 = __uint_as_float(self << 16);
    float ay0 = __uint_as_float(self & 0xffff0000u);
    float ax1 = 0.f, ay1 = 0.f;
    for (; j < end; j += 32) {
        int2 e[32];
        u32 p[32];
#pragma unroll
        for (int u = 0; u < 32; ++u) {
            int idx = j + u;
            int c = (idx < end) ? idx : (end - 1);  // uniform: stays scalar
            e[u] = scev[c];
            if (idx >= end) e[u].y = 0;  // inactive slot contributes 0
        }
#pragma unroll
        for (int u = 0; u < 32; ++u) p[u] = featb[e[u].x * 64 + lane];
#pragma unroll
        for (int u = 0; u < 32; ++u) {
            float v = __int_as_float(e[u].y);
            float lo = __uint_as_float(p[u] << 16);
            float hi = __uint_as_float(p[u] & 0xffff0000u);
            if (u & 1) {
                ax1 += v * lo;
                ay1 += v * hi;
            } else {
                ax0 += v * lo;
                ay0 += v * hi;
            }
        }
    }
    float accx = ax0 + ax1;
    float accy = ay0 + ay1;
    Xb[wid * 64 + lane] = (u32)f2bf(accx) | ((u32)f2bf(accy) << 16);
}

// ---------------- fused MFMA GEMM: out = relu(X@W1+b1)@W2 + b2 ----------------
// Stage 1: W1 staged in LDS, MFMA -> bias+ReLU. H never touches HBM:
// C-fragments packed as bf16 u32-pairs into a TRANSPOSED LDS tile Ht[col][row]
// aliased over Ws (W1 dead after stage 1; barrier-separated). Stage-2
// A-fragments read Ht[k][l16] conflict-free; B-fragments stream straight from
// global W2t (32 KB, L2-resident). Saves the 51.2 MB Hb round-trip + a launch.

__global__ __launch_bounds__(256, 2) void gemm_fused(
    const u16* __restrict__ Xb, const u16* __restrict__ W1t,
    const float* __restrict__ b1, const u16* __restrict__ W2t,
    const float* __restrict__ b2, float* __restrict__ outf) {
    __shared__ u16 Ws[128][136];               // 34816 B; stage 2 aliases Ht over it
    u16(*Ht)[130] = (u16(*)[130]) & Ws[0][0];  // 128x130 = 33280 B <= 34816

    int t = threadIdx.x;
    {
        const uint4* wsrc = (const uint4*)W1t;
#pragma unroll
        for (int i = 0; i < 8; ++i) {
            int f = t + 256 * i;
            *(uint4*)&Ws[f >> 4][(f & 15) << 3] = wsrc[f];
        }
    }
    __syncthreads();

    int w = t >> 6, lane = t & 63;
    int quad = lane >> 4, l16 = lane & 15;
    int row0 = blockIdx.x * 128 + w * 32;

    f32x4 acc[2][8];
#pragma unroll
    for (int rt = 0; rt < 2; ++rt)
#pragma unroll
        for (int ct = 0; ct < 8; ++ct) acc[rt][ct] = (f32x4){0.f, 0.f, 0.f, 0.f};

    int ra = row0 + l16;
    int rb = row0 + 16 + l16;
    if (ra > N_NODES - 1) ra = N_NODES - 1;
    if (rb > N_NODES - 1) rb = N_NODES - 1;
    const u16* pa = Xb + (size_t)ra * D + quad * 8;
    const u16* pb = Xb + (size_t)rb * D + quad * 8;

#pragma unroll
    for (int kb = 0; kb < 128; kb += 32) {
        bf16x8 a0 = *(const bf16x8*)(pa + kb);
        bf16x8 a1 = *(const bf16x8*)(pb + kb);
#pragma unroll
        for (int ct = 0; ct < 8; ++ct) {
            bf16x8 b = *(const bf16x8*)&Ws[ct * 16 + l16][kb + quad * 8];
            acc[0][ct] = __builtin_amdgcn_mfma_f32_16x16x32_bf16(a0, b, acc[0][ct], 0, 0, 0);
            acc[1][ct] = __builtin_amdgcn_mfma_f32_16x16x32_bf16(a1, b, acc[1][ct], 0, 0, 0);
        }
    }

    float bv1[8];
#pragma unroll
    for (int ct = 0; ct < 8; ++ct) bv1[ct] = b1[ct * 16 + l16];

    __syncthreads();  // all W1 reads complete before Ht overwrites Ws

    int hbase = w * 32;  // this wave's local row base
#pragma unroll
    for (int rt = 0; rt < 2; ++rt) {
#pragma unroll
        for (int ct = 0; ct < 8; ++ct) {
            float v0 = fmaxf(acc[rt][ct][0] + bv1[ct], 0.f);
            float v1 = fmaxf(acc[rt][ct][1] + bv1[ct], 0.f);
            float v2 = fmaxf(acc[rt][ct][2] + bv1[ct], 0.f);
            float v3 = fmaxf(acc[rt][ct][3] + bv1[ct], 0.f);
            u16* dst = &Ht[ct * 16 + l16][hbase + rt * 16 + quad * 4];
            ((u32*)dst)[0] = (u32)f2bf(v0) | ((u32)f2bf(v1) << 16);
            ((u32*)dst)[1] = (u32)f2bf(v2) | ((u32)f2bf(v3) << 16);
        }
    }
    __syncthreads();

    f32x4 acc2[2][8];
#pragma unroll
    for (int rt = 0; rt < 2; ++rt)
#pragma unroll
        for (int ct = 0; ct < 8; ++ct) acc2[rt][ct] = (f32x4){0.f, 0.f, 0.f, 0.f};

#pragma unroll
    for (int kb = 0; kb < 128; kb += 32) {
        bf16x8 a0, a1;
#pragma unroll
        for (int i = 0; i < 8; ++i) {
            a0[i] = (short)Ht[kb + quad * 8 + i][hbase + l16];
            a1[i] = (short)Ht[kb + quad * 8 + i][hbase + 16 + l16];
        }
#pragma unroll
        for (int ct = 0; ct < 8; ++ct) {
            bf16x8 b = *(const bf16x8*)(W2t + (size_t)(ct * 16 + l16) * D + kb + quad * 8);
            acc2[0][ct] = __builtin_amdgcn_mfma_f32_16x16x32_bf16(a0, b, acc2[0][ct], 0, 0, 0);
            acc2[1][ct] = __builtin_amdgcn_mfma_f32_16x16x32_bf16(a1, b, acc2[1][ct], 0, 0, 0);
        }
    }

    float bv2[8];
#pragma unroll
    for (int ct = 0; ct < 8; ++ct) bv2[ct] = b2[ct * 16 + l16];

#pragma unroll
    for (int rt = 0; rt < 2; ++rt) {
#pragma unroll
        for (int r = 0; r < 4; ++r) {
            int row = row0 + rt * 16 + quad * 4 + r;
            if (row >= N_NODES) continue;
#pragma unroll
            for (int ct = 0; ct < 8; ++ct) {
                outf[(size_t)row * D + ct * 16 + l16] = acc2[rt][ct][r] + bv2[ct];
            }
        }
    }
}

extern "C" void kernel_launch(void* const* d_in, const int* in_sizes, int n_in,
                              void* d_out, int out_size, void* d_ws, size_t ws_size,
                              hipStream_t stream) {
    const int* indices = (const int*)d_in[0];      // [2, E]
    const float* values = (const float*)d_in[1];   // [E]
    const float* features = (const float*)d_in[2]; // [N, 128]
    const float* W1 = (const float*)d_in[3];
    const float* b1 = (const float*)d_in[4];
    const float* W2 = (const float*)d_in[5];
    const float* b2 = (const float*)d_in[6];

    const int* row = indices;
    const int* col = indices + N_EDGES;

    // ws (ints): coarseCount[CB*16] pad | rowRange[N] int2 | scev[CB*CCAP] int2 |
    //            Xb[N*64] u32 | W1t/W2t u16     total ~40.5 MB
    int* wsI = (int*)d_ws;
    int* coarseCount = wsI;                        // CB*16 = 1568 ints (1/line)
    int2* rowRange = (int2*)(wsI + 1600);          // 800 KB
    int2* scev = (int2*)(wsI + 1600 + 2 * N_NODES);  // 14.05 MB
    u32* Xb = (u32*)(wsI + 1600 + 2 * N_NODES + 2 * CB * CCAP);  // 25.6 MB, 16B-aligned
    u16* W1t = (u16*)(Xb + (size_t)N_NODES * 64);
    u16* W2t = W1t + 16384;

    // d_out: binned[CB*CCAP] int2 (14.05 MB, dead after sortk) lower part;
    // featb (bf16 features, 25.6 MB, dead after spmm) upper half;
    // gemm_fused overwrites everything with outf.
    int2* binned = (int2*)d_out;
    u32* featb = (u32*)((char*)d_out + (size_t)N_NODES * D * 2);
    float* outf = (float*)d_out;

    hipMemsetAsync(coarseCount, 0, CB * 16 * sizeof(int), stream);

    prep<<<BIN_BLKS + CF_BLKS + CW_BLKS, 256, 0, stream>>>(
        features, featb, W1, W2, W1t, W2t, row, col, values, coarseCount, binned);

    sortk<<<CB, 1024, 0, stream>>>(binned, coarseCount, rowRange, scev);

    spmm_bf16<<<(N_NODES * 64 + 255) / 256, 256, 0, stream>>>(scev, rowRange, featb, Xb);

    gemm_fused<<<(N_NODES + 127) / 128, 256, 0, stream>>>(
        (const u16*)Xb, W1t, b1, W2t, b2, outf);
}

// Round 9
// 254.435 us; speedup vs baseline: 1.7022x; 1.0071x over previous
//
#include <hip/hip_runtime.h>

#define N_NODES 100000
#define N_EDGES 1600000
#define D 128
#define CB 98       // coarse buckets of 1024 rows (ceil(100000/1024))
#define CCAP 17920  // per-bucket capacity: mean 16384, sigma 128 -> +12 sigma

typedef unsigned short u16;
typedef unsigned int u32;
typedef __attribute__((ext_vector_type(8))) short bf16x8;
typedef __attribute__((ext_vector_type(4))) float f32x4;

__device__ __forceinline__ u16 f2bf(float f) {
    u32 u = __float_as_uint(f);
    u += 0x7fffu + ((u >> 16) & 1u);  // round-to-nearest-even
    return (u16)(u >> 16);
}

// ---------------- prep_bin: coarse edge binning ONLY (391 blocks) ----------------
// ROUND-8 SPLIT: binning is sortk's sole dependency; the 6378 convert blocks
// that used to share this launch delayed sortk's start by the full convert
// duration. Binning alone = 391 blocks -> starts and finishes fast; converts
// move into sortk_conv's launch as backfill (see below).
// Per 4096-edge block: LDS hist over 98 counters, ONE returning device atomic
// per (block,bucket); coarseCount padded 1/cacheline; ~42-edge consecutive
// runs per bucket -> near-full-line scatter writes.

#define BIN_BLKS 391  // ceil(E/4096)

__global__ __launch_bounds__(256) void prep_bin(
    const int* __restrict__ row, const int* __restrict__ col,
    const float* __restrict__ val,
    int* __restrict__ coarseCount, int2* __restrict__ binned) {
    __shared__ int h[CB];
    __shared__ int lb[CB];
    int bid = blockIdx.x;
    int t = threadIdx.x;

    if (t < CB) h[t] = 0;
    __syncthreads();
    int base = bid * 4096;
    int r[16];
#pragma unroll
    for (int i = 0; i < 16; ++i) {
        int e = base + i * 256 + t;
        r[i] = (e < N_EDGES) ? row[e] : -1;
        if (r[i] >= 0) atomicAdd(&h[r[i] >> 10], 1);
    }
    __syncthreads();
    if (t < CB) {
        int c = h[t];
        lb[t] = c ? atomicAdd(&coarseCount[t * 16], c) : 0;  // padded: 1/line
        h[t] = 0;                                            // reuse as cursor
    }
    __syncthreads();
#pragma unroll
    for (int i = 0; i < 16; ++i) {
        if (r[i] < 0) continue;
        int e = base + i * 256 + t;
        int cb = r[i] >> 10;
        int pos = cb * CCAP + lb[cb] + atomicAdd(&h[cb], 1);
        int2 ev;
        ev.x = col[e] | ((r[i] & 1023) << 17);  // col < 2^17, row-local 10b
        ev.y = __float_as_int(val[e]);
        binned[pos] = ev;
    }
}

// ---------------- sortk_conv: bucket sort (98 blocks) + converts backfill ------
// Blocks [0,98): one 1024-thread block per coarse bucket — LDS hist over 1024
// row-locals -> shuffle-hierarchical scan -> rowRange -> scatter into the
// bucket's padded scev window. Only 98 blocks -> 150+ CUs would sit idle, so
// blocks [98,1661) convert features fp32->bf16 and [1661,1693) transpose W1/W2
// CONCURRENTLY (converts are only needed before spmm, which follows this
// kernel anyway). Streaming converts (~77MB) hide under the latency-bound sort.

#define SORT_BLKS 98
#define CVF_BLKS 1563  // ceil(N*D/8 / 1024)
#define CVW_BLKS 32    // 32768 / 1024

__global__ __launch_bounds__(1024) void sortk_conv(
    const int2* __restrict__ binned, const int* __restrict__ coarseCount,
    int2* __restrict__ rowRange, int2* __restrict__ scev,
    const float* __restrict__ features, u32* __restrict__ featb,
    const float* __restrict__ W1, const float* __restrict__ W2,
    u16* __restrict__ W1t, u16* __restrict__ W2t) {
    __shared__ int h[1024];
    __shared__ int cur[1024];
    __shared__ int wsum[16];
    __shared__ int wbase[16];
    int b = blockIdx.x, t = threadIdx.x;

    if (b >= SORT_BLKS) {
        int cid = b - SORT_BLKS;
        if (cid < CVF_BLKS) {
            // features fp32 [N,128] -> bf16 packed (word j = cols {2j,2j+1})
            int idx = cid * 1024 + t;  // [0, N*D/8)
            if (idx < N_NODES * D / 8) {
                const float4* f4 = (const float4*)features;
                float4 a = f4[idx * 2], bb = f4[idx * 2 + 1];
                uint4 o;
                o.x = (u32)f2bf(a.x) | ((u32)f2bf(a.y) << 16);
                o.y = (u32)f2bf(a.z) | ((u32)f2bf(a.w) << 16);
                o.z = (u32)f2bf(bb.x) | ((u32)f2bf(bb.y) << 16);
                o.w = (u32)f2bf(bb.z) | ((u32)f2bf(bb.w) << 16);
                ((uint4*)featb)[idx] = o;
            }
        } else {
            // W[k][n] fp32 -> Wt[n][k] bf16, both 128x128
            int flat = (cid - CVF_BLKS) * 1024 + t;  // [0, 32768)
            int m = flat >> 14;
            int idx = flat & 16383;
            int n = idx & 127;
            int k = idx >> 7;
            const float* src = m ? W2 : W1;
            u16* dst = m ? W2t : W1t;
            dst[n * 128 + k] = f2bf(src[k * 128 + n]);
        }
        return;
    }

    int lane = t & 63, wv = t >> 6;
    int row0 = b << 10;
    int lo = b * CCAP;
    int cnt = coarseCount[b * 16];

    h[t] = 0;
    __syncthreads();
    for (int i = t; i < cnt; i += 1024)
        atomicAdd(&h[((u32)binned[lo + i].x) >> 17], 1);
    __syncthreads();

    int c = h[t];
    int x = c;  // inclusive scan within wave
#pragma unroll
    for (int d = 1; d < 64; d <<= 1) {
        int y = __shfl_up(x, d);
        if (lane >= d) x += y;
    }
    if (lane == 63) wsum[wv] = x;
    __syncthreads();
    if (t < 16) {
        int s = wsum[t], sx = s;
#pragma unroll
        for (int d = 1; d < 16; d <<= 1) {
            int y = __shfl_up(sx, d);
            if (lane >= d) sx += y;
        }
        wbase[t] = sx - s;  // exclusive base per wave
    }
    __syncthreads();
    int start = lo + wbase[wv] + (x - c);  // absolute exclusive prefix
    if (row0 + t < N_NODES) rowRange[row0 + t] = make_int2(start, start + c);
    cur[t] = start;
    __syncthreads();

    for (int i = t; i < cnt; i += 1024) {
        int2 ev = binned[lo + i];
        int rl = ((u32)ev.x) >> 17;
        int pos = atomicAdd(&cur[rl], 1);
        scev[pos] = make_int2(ev.x & 0x1FFFF, ev.y);
    }
}

// ---------------- SpMM (bf16 gather): one wave per row ----------------
// Xb[r] = bf16( featb[r] + sum_j v_j * featb[col_j] )
// ROUND-8: byte-exact revert to the round-2 structure (61.5us proven).
// Five variants (fenced VGPR dbuf, relaxed-cap dbuf, LDS staging, batch-32)
// all lost: the compiler caps useful per-wave depth at ~16 loads, and at
// ~7.7 TB/s delivered-to-CU this loop sits at ~85% of the random-256B-gather
// ceiling. wid wave-uniform via readfirstlane -> rowRange/scev stay scalar;
// clamped 16-deep batches (dup slots hit the end-1 line in L1).

__global__ __launch_bounds__(256) void spmm_bf16(
    const int2* __restrict__ scev, const int2* __restrict__ rowRange,
    const u32* __restrict__ featb, u32* __restrict__ Xb) {
    int wid0 = (blockIdx.x * blockDim.x + threadIdx.x) >> 6;
    int wid = __builtin_amdgcn_readfirstlane(wid0);
    int lane = threadIdx.x & 63;
    if (wid >= N_NODES) return;
    int2 rr = rowRange[wid];
    int j = rr.x, end = rr.y;
    u32 self = featb[wid * 64 + lane];
    float ax0 = __uint_as_float(self << 16);
    float ay0 = __uint_as_float(self & 0xffff0000u);
    float ax1 = 0.f, ay1 = 0.f;
    for (; j < end; j += 16) {
        int2 e[16];
        u32 p[16];
#pragma unroll
        for (int u = 0; u < 16; ++u) {
            int idx = j + u;
            int c = (idx < end) ? idx : (end - 1);  // uniform: stays scalar
            e[u] = scev[c];
            if (idx >= end) e[u].y = 0;  // inactive slot contributes 0
        }
#pragma unroll
        for (int u = 0; u < 16; ++u) p[u] = featb[e[u].x * 64 + lane];
#pragma unroll
        for (int u = 0; u < 16; ++u) {
            float v = __int_as_float(e[u].y);
            float lo = __uint_as_float(p[u] << 16);
            float hi = __uint_as_float(p[u] & 0xffff0000u);
            if (u & 1) {
                ax1 += v * lo;
                ay1 += v * hi;
            } else {
                ax0 += v * lo;
                ay0 += v * hi;
            }
        }
    }
    float accx = ax0 + ax1;
    float accy = ay0 + ay1;
    Xb[wid * 64 + lane] = (u32)f2bf(accx) | ((u32)f2bf(accy) << 16);
}

// ---------------- fused MFMA GEMM: out = relu(X@W1+b1)@W2 + b2 ----------------
// Stage 1: W1 staged in LDS, MFMA -> bias+ReLU. H never touches HBM:
// C-fragments packed as bf16 u32-pairs into a TRANSPOSED LDS tile Ht[col][row]
// aliased over Ws (W1 dead after stage 1; barrier-separated). Stage-2
// A-fragments read Ht[k][l16] conflict-free; B-fragments stream straight from
// global W2t (32 KB, L2-resident). Saves the 51.2 MB Hb round-trip + a launch.

__global__ __launch_bounds__(256, 2) void gemm_fused(
    const u16* __restrict__ Xb, const u16* __restrict__ W1t,
    const float* __restrict__ b1, const u16* __restrict__ W2t,
    const float* __restrict__ b2, float* __restrict__ outf) {
    __shared__ u16 Ws[128][136];               // 34816 B; stage 2 aliases Ht over it
    u16(*Ht)[130] = (u16(*)[130]) & Ws[0][0];  // 128x130 = 33280 B <= 34816

    int t = threadIdx.x;
    {
        const uint4* wsrc = (const uint4*)W1t;
#pragma unroll
        for (int i = 0; i < 8; ++i) {
            int f = t + 256 * i;
            *(uint4*)&Ws[f >> 4][(f & 15) << 3] = wsrc[f];
        }
    }
    __syncthreads();

    int w = t >> 6, lane = t & 63;
    int quad = lane >> 4, l16 = lane & 15;
    int row0 = blockIdx.x * 128 + w * 32;

    f32x4 acc[2][8];
#pragma unroll
    for (int rt = 0; rt < 2; ++rt)
#pragma unroll
        for (int ct = 0; ct < 8; ++ct) acc[rt][ct] = (f32x4){0.f, 0.f, 0.f, 0.f};

    int ra = row0 + l16;
    int rb = row0 + 16 + l16;
    if (ra > N_NODES - 1) ra = N_NODES - 1;
    if (rb > N_NODES - 1) rb = N_NODES - 1;
    const u16* pa = Xb + (size_t)ra * D + quad * 8;
    const u16* pb = Xb + (size_t)rb * D + quad * 8;

#pragma unroll
    for (int kb = 0; kb < 128; kb += 32) {
        bf16x8 a0 = *(const bf16x8*)(pa + kb);
        bf16x8 a1 = *(const bf16x8*)(pb + kb);
#pragma unroll
        for (int ct = 0; ct < 8; ++ct) {
            bf16x8 b = *(const bf16x8*)&Ws[ct * 16 + l16][kb + quad * 8];
            acc[0][ct] = __builtin_amdgcn_mfma_f32_16x16x32_bf16(a0, b, acc[0][ct], 0, 0, 0);
            acc[1][ct] = __builtin_amdgcn_mfma_f32_16x16x32_bf16(a1, b, acc[1][ct], 0, 0, 0);
        }
    }

    float bv1[8];
#pragma unroll
    for (int ct = 0; ct < 8; ++ct) bv1[ct] = b1[ct * 16 + l16];

    __syncthreads();  // all W1 reads complete before Ht overwrites Ws

    int hbase = w * 32;  // this wave's local row base
#pragma unroll
    for (int rt = 0; rt < 2; ++rt) {
#pragma unroll
        for (int ct = 0; ct < 8; ++ct) {
            float v0 = fmaxf(acc[rt][ct][0] + bv1[ct], 0.f);
            float v1 = fmaxf(acc[rt][ct][1] + bv1[ct], 0.f);
            float v2 = fmaxf(acc[rt][ct][2] + bv1[ct], 0.f);
            float v3 = fmaxf(acc[rt][ct][3] + bv1[ct], 0.f);
            u16* dst = &Ht[ct * 16 + l16][hbase + rt * 16 + quad * 4];
            ((u32*)dst)[0] = (u32)f2bf(v0) | ((u32)f2bf(v1) << 16);
            ((u32*)dst)[1] = (u32)f2bf(v2) | ((u32)f2bf(v3) << 16);
        }
    }
    __syncthreads();

    f32x4 acc2[2][8];
#pragma unroll
    for (int rt = 0; rt < 2; ++rt)
#pragma unroll
        for (int ct = 0; ct < 8; ++ct) acc2[rt][ct] = (f32x4){0.f, 0.f, 0.f, 0.f};

#pragma unroll
    for (int kb = 0; kb < 128; kb += 32) {
        bf16x8 a0, a1;
#pragma unroll
        for (int i = 0; i < 8; ++i) {
            a0[i] = (short)Ht[kb + quad * 8 + i][hbase + l16];
            a1[i] = (short)Ht[kb + quad * 8 + i][hbase + 16 + l16];
        }
#pragma unroll
        for (int ct = 0; ct < 8; ++ct) {
            bf16x8 b = *(const bf16x8*)(W2t + (size_t)(ct * 16 + l16) * D + kb + quad * 8);
            acc2[0][ct] = __builtin_amdgcn_mfma_f32_16x16x32_bf16(a0, b, acc2[0][ct], 0, 0, 0);
            acc2[1][ct] = __builtin_amdgcn_mfma_f32_16x16x32_bf16(a1, b, acc2[1][ct], 0, 0, 0);
        }
    }

    float bv2[8];
#pragma unroll
    for (int ct = 0; ct < 8; ++ct) bv2[ct] = b2[ct * 16 + l16];

#pragma unroll
    for (int rt = 0; rt < 2; ++rt) {
#pragma unroll
        for (int r = 0; r < 4; ++r) {
            int row = row0 + rt * 16 + quad * 4 + r;
            if (row >= N_NODES) continue;
#pragma unroll
            for (int ct = 0; ct < 8; ++ct) {
                outf[(size_t)row * D + ct * 16 + l16] = acc2[rt][ct][r] + bv2[ct];
            }
        }
    }
}

extern "C" void kernel_launch(void* const* d_in, const int* in_sizes, int n_in,
                              void* d_out, int out_size, void* d_ws, size_t ws_size,
                              hipStream_t stream) {
    const int* indices = (const int*)d_in[0];      // [2, E]
    const float* values = (const float*)d_in[1];   // [E]
    const float* features = (const float*)d_in[2]; // [N, 128]
    const float* W1 = (const float*)d_in[3];
    const float* b1 = (const float*)d_in[4];
    const float* W2 = (const float*)d_in[5];
    const float* b2 = (const float*)d_in[6];

    const int* row = indices;
    const int* col = indices + N_EDGES;

    // ws (ints): coarseCount[CB*16] pad | rowRange[N] int2 | scev[CB*CCAP] int2 |
    //            Xb[N*64] u32 | W1t/W2t u16     total ~40.5 MB
    int* wsI = (int*)d_ws;
    int* coarseCount = wsI;                        // CB*16 = 1568 ints (1/line)
    int2* rowRange = (int2*)(wsI + 1600);          // 800 KB
    int2* scev = (int2*)(wsI + 1600 + 2 * N_NODES);  // 14.05 MB
    u32* Xb = (u32*)(wsI + 1600 + 2 * N_NODES + 2 * CB * CCAP);  // 25.6 MB, 16B-aligned
    u16* W1t = (u16*)(Xb + (size_t)N_NODES * 64);
    u16* W2t = W1t + 16384;

    // d_out: binned[CB*CCAP] int2 (14.05 MB, dead after sortk_conv) lower part;
    // featb (bf16 features, 25.6 MB, dead after spmm) upper half;
    // gemm_fused overwrites everything with outf.
    int2* binned = (int2*)d_out;
    u32* featb = (u32*)((char*)d_out + (size_t)N_NODES * D * 2);
    float* outf = (float*)d_out;

    hipMemsetAsync(coarseCount, 0, CB * 16 * sizeof(int), stream);

    prep_bin<<<BIN_BLKS, 256, 0, stream>>>(row, col, values, coarseCount, binned);

    sortk_conv<<<SORT_BLKS + CVF_BLKS + CVW_BLKS, 1024, 0, stream>>>(
        binned, coarseCount, rowRange, scev, features, featb, W1, W2, W1t, W2t);

    spmm_bf16<<<(N_NODES * 64 + 255) / 256, 256, 0, stream>>>(scev, rowRange, featb, Xb);

    gemm_fused<<<(N_NODES + 127) / 128, 256, 0, stream>>>(
        (const u16*)Xb, W1t, b1, W2t, b2, outf);
}

// Round 10
// 254.109 us; speedup vs baseline: 1.7044x; 1.0013x over previous
//
#include <hip/hip_runtime.h>

#define N_NODES 100000
#define N_EDGES 1600000
#define D 128
#define CB 98       // coarse buckets of 1024 rows (ceil(100000/1024))
#define CCAP 17920  // per-bucket capacity: mean 16384, sigma 128 -> +12 sigma

typedef unsigned short u16;
typedef unsigned int u32;
typedef __attribute__((ext_vector_type(8))) short bf16x8;
typedef __attribute__((ext_vector_type(4))) float f32x4;
typedef __attribute__((ext_vector_type(2))) float f32x2;

__device__ __forceinline__ u16 f2bf(float f) {
    u32 u = __float_as_uint(f);
    u += 0x7fffu + ((u >> 16) & 1u);  // round-to-nearest-even
    return (u16)(u >> 16);
}

// ---------------- prep_bin: coarse edge binning ONLY ----------------
// ROUND-9: 2048 edges/block (782 blocks = 3 blocks/CU, 2x the waves of the
// 391-block version — this kernel is latency-bound, not BW-bound) and a
// SINGLE edge read: col/val cached in regs during the hist phase, saving the
// 12.8MB scatter-phase re-read. Global atomics: 782x98 = 77K on padded lines.
// Bucket runs ~21 edges (~168B) -> write amp still minor.

#define BIN_BLKS 782  // ceil(E/2048)

__global__ __launch_bounds__(256) void prep_bin(
    const int* __restrict__ row, const int* __restrict__ col,
    const float* __restrict__ val,
    int* __restrict__ coarseCount, int2* __restrict__ binned) {
    __shared__ int h[CB];
    __shared__ int lb[CB];
    int bid = blockIdx.x;
    int t = threadIdx.x;

    if (t < CB) h[t] = 0;
    __syncthreads();
    int base = bid * 2048;
    int r[8], c[8];
    float v[8];
#pragma unroll
    for (int i = 0; i < 8; ++i) {
        int e = base + i * 256 + t;
        bool ok = (e < N_EDGES);
        r[i] = ok ? row[e] : -1;
        c[i] = ok ? col[e] : 0;
        v[i] = ok ? val[e] : 0.f;
        if (ok) atomicAdd(&h[r[i] >> 10], 1);
    }
    __syncthreads();
    if (t < CB) {
        int cc = h[t];
        lb[t] = cc ? atomicAdd(&coarseCount[t * 16], cc) : 0;  // padded: 1/line
        h[t] = 0;                                              // reuse as cursor
    }
    __syncthreads();
#pragma unroll
    for (int i = 0; i < 8; ++i) {
        if (r[i] < 0) continue;
        int cb = r[i] >> 10;
        int pos = cb * CCAP + lb[cb] + atomicAdd(&h[cb], 1);
        int2 ev;
        ev.x = c[i] | ((r[i] & 1023) << 17);  // col < 2^17, row-local 10b
        ev.y = __float_as_int(v[i]);
        binned[pos] = ev;
    }
}

// ---------------- sortk_conv: bucket sort (98 blocks) + converts backfill ------
// Blocks [0,98): one 1024-thread block per coarse bucket — LDS hist over 1024
// row-locals -> shuffle-hierarchical scan -> rowRange -> scatter into the
// bucket's padded scev window. Blocks [98,1661) convert features fp32->bf16
// and [1661,1693) transpose W1/W2 concurrently (needed only before spmm).

#define SORT_BLKS 98
#define CVF_BLKS 1563  // ceil(N*D/8 / 1024)
#define CVW_BLKS 32    // 32768 / 1024

__global__ __launch_bounds__(1024) void sortk_conv(
    const int2* __restrict__ binned, const int* __restrict__ coarseCount,
    int2* __restrict__ rowRange, int2* __restrict__ scev,
    const float* __restrict__ features, u32* __restrict__ featb,
    const float* __restrict__ W1, const float* __restrict__ W2,
    u16* __restrict__ W1t, u16* __restrict__ W2t) {
    __shared__ int h[1024];
    __shared__ int cur[1024];
    __shared__ int wsum[16];
    __shared__ int wbase[16];
    int b = blockIdx.x, t = threadIdx.x;

    if (b >= SORT_BLKS) {
        int cid = b - SORT_BLKS;
        if (cid < CVF_BLKS) {
            // features fp32 [N,128] -> bf16 packed (word j = cols {2j,2j+1})
            int idx = cid * 1024 + t;  // [0, N*D/8)
            if (idx < N_NODES * D / 8) {
                const float4* f4 = (const float4*)features;
                float4 a = f4[idx * 2], bb = f4[idx * 2 + 1];
                uint4 o;
                o.x = (u32)f2bf(a.x) | ((u32)f2bf(a.y) << 16);
                o.y = (u32)f2bf(a.z) | ((u32)f2bf(a.w) << 16);
                o.z = (u32)f2bf(bb.x) | ((u32)f2bf(bb.y) << 16);
                o.w = (u32)f2bf(bb.z) | ((u32)f2bf(bb.w) << 16);
                ((uint4*)featb)[idx] = o;
            }
        } else {
            // W[k][n] fp32 -> Wt[n][k] bf16, both 128x128
            int flat = (cid - CVF_BLKS) * 1024 + t;  // [0, 32768)
            int m = flat >> 14;
            int idx = flat & 16383;
            int n = idx & 127;
            int k = idx >> 7;
            const float* src = m ? W2 : W1;
            u16* dst = m ? W2t : W1t;
            dst[n * 128 + k] = f2bf(src[k * 128 + n]);
        }
        return;
    }

    int lane = t & 63, wv = t >> 6;
    int row0 = b << 10;
    int lo = b * CCAP;
    int cnt = coarseCount[b * 16];

    h[t] = 0;
    __syncthreads();
    for (int i = t; i < cnt; i += 1024)
        atomicAdd(&h[((u32)binned[lo + i].x) >> 17], 1);
    __syncthreads();

    int c = h[t];
    int x = c;  // inclusive scan within wave
#pragma unroll
    for (int d = 1; d < 64; d <<= 1) {
        int y = __shfl_up(x, d);
        if (lane >= d) x += y;
    }
    if (lane == 63) wsum[wv] = x;
    __syncthreads();
    if (t < 16) {
        int s = wsum[t], sx = s;
#pragma unroll
        for (int d = 1; d < 16; d <<= 1) {
            int y = __shfl_up(sx, d);
            if (lane >= d) sx += y;
        }
        wbase[t] = sx - s;  // exclusive base per wave
    }
    __syncthreads();
    int start = lo + wbase[wv] + (x - c);  // absolute exclusive prefix
    if (row0 + t < N_NODES) rowRange[row0 + t] = make_int2(start, start + c);
    cur[t] = start;
    __syncthreads();

    for (int i = t; i < cnt; i += 1024) {
        int2 ev = binned[lo + i];
        int rl = ((u32)ev.x) >> 17;
        int pos = atomicAdd(&cur[rl], 1);
        scev[pos] = make_int2(ev.x & 0x1FFFF, ev.y);
    }
}

// ---------------- SpMM (bf16 gather): one wave per row ----------------
// Xb[r] = bf16( featb[r] + sum_j v_j * featb[col_j] )
// Round-2 proven structure (61.5us): wid wave-uniform via readfirstlane ->
// rowRange/scev stay scalar; clamped 16-deep batches (dup slots hit L1).
// ROUND-9 (isolated change): f32x2 packed accumulate so the consume emits
// v_pk_fma_f32 — 3 VALU ops/edge (shift, and, pk_fma) instead of 4. VALUBusy
// was 50%; if consume-VALU is half the serialization this is ~-8%. Flat
// result = spmm is pure latency-bound (closes the question).

__global__ __launch_bounds__(256) void spmm_bf16(
    const int2* __restrict__ scev, const int2* __restrict__ rowRange,
    const u32* __restrict__ featb, u32* __restrict__ Xb) {
    int wid0 = (blockIdx.x * blockDim.x + threadIdx.x) >> 6;
    int wid = __builtin_amdgcn_readfirstlane(wid0);
    int lane = threadIdx.x & 63;
    if (wid >= N_NODES) return;
    int2 rr = rowRange[wid];
    int j = rr.x, end = rr.y;
    u32 self = featb[wid * 64 + lane];
    f32x2 acc0, acc1;
    acc0.x = __uint_as_float(self << 16);
    acc0.y = __uint_as_float(self & 0xffff0000u);
    acc1.x = 0.f;
    acc1.y = 0.f;
    for (; j < end; j += 16) {
        int2 e[16];
        u32 p[16];
#pragma unroll
        for (int u = 0; u < 16; ++u) {
            int idx = j + u;
            int c = (idx < end) ? idx : (end - 1);  // uniform: stays scalar
            e[u] = scev[c];
            if (idx >= end) e[u].y = 0;  // inactive slot contributes 0
        }
#pragma unroll
        for (int u = 0; u < 16; ++u) p[u] = featb[e[u].x * 64 + lane];
#pragma unroll
        for (int u = 0; u < 16; ++u) {
            float v = __int_as_float(e[u].y);
            f32x2 pv, vv;
            pv.x = __uint_as_float(p[u] << 16);
            pv.y = __uint_as_float(p[u] & 0xffff0000u);
            vv.x = v;
            vv.y = v;
            if (u & 1) acc1 += vv * pv;
            else       acc0 += vv * pv;
        }
    }
    float accx = acc0.x + acc1.x;
    float accy = acc0.y + acc1.y;
    Xb[wid * 64 + lane] = (u32)f2bf(accx) | ((u32)f2bf(accy) << 16);
}

// ---------------- fused MFMA GEMM: out = relu(X@W1+b1)@W2 + b2 ----------------
// Stage 1: W1 staged in LDS, MFMA -> bias+ReLU. H never touches HBM:
// C-fragments packed as bf16 u32-pairs into a TRANSPOSED LDS tile Ht[col][row]
// aliased over Ws (W1 dead after stage 1; barrier-separated). Stage-2
// A-fragments read Ht[k][l16] conflict-free; B-fragments stream from global
// W2t (32 KB, L2-resident).
// ROUND-9: launch_bounds (256,2)->(256,3): 3 blocks/CU (LDS 104KB<160KB,
// VGPR cap ~170 vs est ~100-120 peak liveness -> no spill expected; spill
// tripwire = WRITE_SIZE balloon on this dispatch). +50% waves to hide the
// global Xb/W2t stream latency.

__global__ __launch_bounds__(256, 3) void gemm_fused(
    const u16* __restrict__ Xb, const u16* __restrict__ W1t,
    const float* __restrict__ b1, const u16* __restrict__ W2t,
    const float* __restrict__ b2, float* __restrict__ outf) {
    __shared__ u16 Ws[128][136];               // 34816 B; stage 2 aliases Ht over it
    u16(*Ht)[130] = (u16(*)[130]) & Ws[0][0];  // 128x130 = 33280 B <= 34816

    int t = threadIdx.x;
    {
        const uint4* wsrc = (const uint4*)W1t;
#pragma unroll
        for (int i = 0; i < 8; ++i) {
            int f = t + 256 * i;
            *(uint4*)&Ws[f >> 4][(f & 15) << 3] = wsrc[f];
        }
    }
    __syncthreads();

    int w = t >> 6, lane = t & 63;
    int quad = lane >> 4, l16 = lane & 15;
    int row0 = blockIdx.x * 128 + w * 32;

    f32x4 acc[2][8];
#pragma unroll
    for (int rt = 0; rt < 2; ++rt)
#pragma unroll
        for (int ct = 0; ct < 8; ++ct) acc[rt][ct] = (f32x4){0.f, 0.f, 0.f, 0.f};

    int ra = row0 + l16;
    int rb = row0 + 16 + l16;
    if (ra > N_NODES - 1) ra = N_NODES - 1;
    if (rb > N_NODES - 1) rb = N_NODES - 1;
    const u16* pa = Xb + (size_t)ra * D + quad * 8;
    const u16* pb = Xb + (size_t)rb * D + quad * 8;

#pragma unroll
    for (int kb = 0; kb < 128; kb += 32) {
        bf16x8 a0 = *(const bf16x8*)(pa + kb);
        bf16x8 a1 = *(const bf16x8*)(pb + kb);
#pragma unroll
        for (int ct = 0; ct < 8; ++ct) {
            bf16x8 b = *(const bf16x8*)&Ws[ct * 16 + l16][kb + quad * 8];
            acc[0][ct] = __builtin_amdgcn_mfma_f32_16x16x32_bf16(a0, b, acc[0][ct], 0, 0, 0);
            acc[1][ct] = __builtin_amdgcn_mfma_f32_16x16x32_bf16(a1, b, acc[1][ct], 0, 0, 0);
        }
    }

    float bv1[8];
#pragma unroll
    for (int ct = 0; ct < 8; ++ct) bv1[ct] = b1[ct * 16 + l16];

    __syncthreads();  // all W1 reads complete before Ht overwrites Ws

    int hbase = w * 32;  // this wave's local row base
#pragma unroll
    for (int rt = 0; rt < 2; ++rt) {
#pragma unroll
        for (int ct = 0; ct < 8; ++ct) {
            float v0 = fmaxf(acc[rt][ct][0] + bv1[ct], 0.f);
            float v1 = fmaxf(acc[rt][ct][1] + bv1[ct], 0.f);
            float v2 = fmaxf(acc[rt][ct][2] + bv1[ct], 0.f);
            float v3 = fmaxf(acc[rt][ct][3] + bv1[ct], 0.f);
            u16* dst = &Ht[ct * 16 + l16][hbase + rt * 16 + quad * 4];
            ((u32*)dst)[0] = (u32)f2bf(v0) | ((u32)f2bf(v1) << 16);
            ((u32*)dst)[1] = (u32)f2bf(v2) | ((u32)f2bf(v3) << 16);
        }
    }
    __syncthreads();

    f32x4 acc2[2][8];
#pragma unroll
    for (int rt = 0; rt < 2; ++rt)
#pragma unroll
        for (int ct = 0; ct < 8; ++ct) acc2[rt][ct] = (f32x4){0.f, 0.f, 0.f, 0.f};

#pragma unroll
    for (int kb = 0; kb < 128; kb += 32) {
        bf16x8 a0, a1;
#pragma unroll
        for (int i = 0; i < 8; ++i) {
            a0[i] = (short)Ht[kb + quad * 8 + i][hbase + l16];
            a1[i] = (short)Ht[kb + quad * 8 + i][hbase + 16 + l16];
        }
#pragma unroll
        for (int ct = 0; ct < 8; ++ct) {
            bf16x8 b = *(const bf16x8*)(W2t + (size_t)(ct * 16 + l16) * D + kb + quad * 8);
            acc2[0][ct] = __builtin_amdgcn_mfma_f32_16x16x32_bf16(a0, b, acc2[0][ct], 0, 0, 0);
            acc2[1][ct] = __builtin_amdgcn_mfma_f32_16x16x32_bf16(a1, b, acc2[1][ct], 0, 0, 0);
        }
    }

    float bv2[8];
#pragma unroll
    for (int ct = 0; ct < 8; ++ct) bv2[ct] = b2[ct * 16 + l16];

#pragma unroll
    for (int rt = 0; rt < 2; ++rt) {
#pragma unroll
        for (int r = 0; r < 4; ++r) {
            int row = row0 + rt * 16 + quad * 4 + r;
            if (row >= N_NODES) continue;
#pragma unroll
            for (int ct = 0; ct < 8; ++ct) {
                outf[(size_t)row * D + ct * 16 + l16] = acc2[rt][ct][r] + bv2[ct];
            }
        }
    }
}

extern "C" void kernel_launch(void* const* d_in, const int* in_sizes, int n_in,
                              void* d_out, int out_size, void* d_ws, size_t ws_size,
                              hipStream_t stream) {
    const int* indices = (const int*)d_in[0];      // [2, E]
    const float* values = (const float*)d_in[1];   // [E]
    const float* features = (const float*)d_in[2]; // [N, 128]
    const float* W1 = (const float*)d_in[3];
    const float* b1 = (const float*)d_in[4];
    const float* W2 = (const float*)d_in[5];
    const float* b2 = (const float*)d_in[6];

    const int* row = indices;
    const int* col = indices + N_EDGES;

    // ws (ints): coarseCount[CB*16] pad | rowRange[N] int2 | scev[CB*CCAP] int2 |
    //            Xb[N*64] u32 | W1t/W2t u16     total ~40.5 MB
    int* wsI = (int*)d_ws;
    int* coarseCount = wsI;                        // CB*16 = 1568 ints (1/line)
    int2* rowRange = (int2*)(wsI + 1600);          // 800 KB
    int2* scev = (int2*)(wsI + 1600 + 2 * N_NODES);  // 14.05 MB
    u32* Xb = (u32*)(wsI + 1600 + 2 * N_NODES + 2 * CB * CCAP);  // 25.6 MB, 16B-aligned
    u16* W1t = (u16*)(Xb + (size_t)N_NODES * 64);
    u16* W2t = W1t + 16384;

    // d_out: binned[CB*CCAP] int2 (14.05 MB, dead after sortk_conv) lower part;
    // featb (bf16 features, 25.6 MB, dead after spmm) upper half;
    // gemm_fused overwrites everything with outf.
    int2* binned = (int2*)d_out;
    u32* featb = (u32*)((char*)d_out + (size_t)N_NODES * D * 2);
    float* outf = (float*)d_out;

    hipMemsetAsync(coarseCount, 0, CB * 16 * sizeof(int), stream);

    prep_bin<<<BIN_BLKS, 256, 0, stream>>>(row, col, values, coarseCount, binned);

    sortk_conv<<<SORT_BLKS + CVF_BLKS + CVW_BLKS, 1024, 0, stream>>>(
        binned, coarseCount, rowRange, scev, features, featb, W1, W2, W1t, W2t);

    spmm_bf16<<<(N_NODES * 64 + 255) / 256, 256, 0, stream>>>(scev, rowRange, featb, Xb);

    gemm_fused<<<(N_NODES + 127) / 128, 256, 0, stream>>>(
        (const u16*)Xb, W1t, b1, W2t, b2, outf);
}